// Round 2
// baseline (751.822 us; speedup 1.0000x reference)
//
#include <hip/hip_runtime.h>

typedef short short8 __attribute__((ext_vector_type(8)));
typedef float floatx4 __attribute__((ext_vector_type(4)));

#define NBATCH 2
#define SEQ 8192
#define NHEAD 16
#define DHEAD 64
#define DIM 1024
#define QKVLD 3072
#define NBUCK 128
#define MROWS 16384
#define QK_SCALE 0.35355339059327379f

static __device__ __forceinline__ unsigned short f2b(float f) {
  unsigned int u = __float_as_uint(f);
  u = (u + 0x7fffu + ((u >> 16) & 1u)) >> 16;
  return (unsigned short)u;
}
static __device__ __forceinline__ float b2f(unsigned short h) {
  return __uint_as_float(((unsigned int)h) << 16);
}

__device__ __forceinline__ void gload_lds16(const void* g, void* l) {
  __builtin_amdgcn_global_load_lds(
      (const __attribute__((address_space(1))) unsigned int*)g,
      (__attribute__((address_space(3))) unsigned int*)l, 16, 0, 0);
}

__global__ void ws_sentinel(float* out, float v) { out[0] = v; }

// Split fp32 -> bf16 hi + bf16 residual lo (vectorized x4).
__global__ void split4(const float4* __restrict__ src, ushort4* __restrict__ hi,
                       ushort4* __restrict__ lo, int n4) {
  const int stride = gridDim.x * blockDim.x;
  for (int i = blockIdx.x * blockDim.x + threadIdx.x; i < n4; i += stride) {
    float4 v = src[i];
    ushort4 h, l;
    h.x = f2b(v.x); l.x = f2b(v.x - b2f(h.x));
    h.y = f2b(v.y); l.y = f2b(v.y - b2f(h.y));
    h.z = f2b(v.z); l.z = f2b(v.z - b2f(h.z));
    h.w = f2b(v.w); l.w = f2b(v.w - b2f(h.w));
    hi[i] = h; lo[i] = l;
  }
}

// C[m][n] = sum_k A[m][k]*B[n][k] over 3 split terms: Ahi*Bhi + Ahi*Blo + Alo*Bhi
// m97 structure: 128x128 tile, BK=32, 4 waves (2x2 of 64x64), 16x16x32 bf16 MFMA.
// EPI=0: fp32 C + bias.  EPI=1: bf16 store to {qb,kb,vb} selected by col/1024.
template <int EPI>
__global__ __launch_bounds__(256) void gemm3(
    const unsigned short* __restrict__ Ahi, const unsigned short* __restrict__ Alo,
    const unsigned short* __restrict__ Bhi, const unsigned short* __restrict__ Blo,
    float* __restrict__ C, unsigned short* __restrict__ qb,
    unsigned short* __restrict__ kb, unsigned short* __restrict__ vb,
    int M, int N, int K, int ldc, const float* __restrict__ bias)
{
  __shared__ unsigned short As[128 * 32];
  __shared__ unsigned short Bs[128 * 32];
  const int t = threadIdx.x;
  const int l = t & 63, w = t >> 6;
  const int wr = w >> 1, wc = w & 1;
  const int m0 = blockIdx.y * 128, n0 = blockIdx.x * 128;
  const int kt = K >> 5;
  const int lr = l & 15, lk = (l >> 4) * 8;
  floatx4 acc[4][4] = {};
  for (int s = 0; s < 3 * kt; ++s) {
    const int seg = s / kt;
    const int ksub = (s - seg * kt) << 5;
    const unsigned short* Ap = (seg == 2) ? Alo : Ahi;
    const unsigned short* Bp = (seg == 1) ? Blo : Bhi;
#pragma unroll
    for (int j = 0; j < 2; ++j) {
      const int u = j * 256 + t;
      const int row = u >> 2, qc = u & 3;
      gload_lds16(Ap + (size_t)(m0 + row) * K + ksub + qc * 8, &As[u * 8]);
      gload_lds16(Bp + (size_t)(n0 + row) * K + ksub + qc * 8, &Bs[u * 8]);
    }
    __syncthreads();
    short8 a[4], b[4];
#pragma unroll
    for (int mi = 0; mi < 4; ++mi)
      a[mi] = *(const short8*)&As[(wr * 64 + mi * 16 + lr) * 32 + lk];
#pragma unroll
    for (int ni = 0; ni < 4; ++ni)
      b[ni] = *(const short8*)&Bs[(wc * 64 + ni * 16 + lr) * 32 + lk];
#pragma unroll
    for (int mi = 0; mi < 4; ++mi)
#pragma unroll
      for (int ni = 0; ni < 4; ++ni)
        acc[mi][ni] = __builtin_amdgcn_mfma_f32_16x16x32_bf16(a[mi], b[ni], acc[mi][ni], 0, 0, 0);
    __syncthreads();
  }
#pragma unroll
  for (int mi = 0; mi < 4; ++mi)
#pragma unroll
    for (int ni = 0; ni < 4; ++ni)
#pragma unroll
      for (int i = 0; i < 4; ++i) {
        const int row = m0 + wr * 64 + mi * 16 + (l >> 4) * 4 + i;
        const int col = n0 + wc * 64 + ni * 16 + lr;
        float v = acc[mi][ni][i];
        if (EPI == 0) {
          if (bias) v += bias[col];
          C[(size_t)row * ldc + col] = v;
        } else {
          const int sel = col >> 10;
          unsigned short* dst = (sel == 0) ? qb : (sel == 1 ? kb : vb);
          dst[(size_t)row * DIM + (col & 1023)] = f2b(v);
        }
      }
}

// Per-bucket: S[d][e] = sum_p psi(k)[p][d] * v[p][e]; ksum[d] = sum_p psi(k)[p][d]
__global__ __launch_bounds__(256) void bucket_stats(
    const unsigned short* __restrict__ kb, const unsigned short* __restrict__ vb,
    float* __restrict__ S, float* __restrict__ ksum)
{
  const int bid = blockIdx.x;           // bh*128 + u
  const int u = bid & 127, bh = bid >> 7;
  const int b = bh >> 4, h = bh & 15;
  const int t = threadIdx.x;
  __shared__ float kps[64][64];
  __shared__ float vv[64][64];
  const size_t rowbase = ((size_t)b * SEQ + (size_t)u * 64) * DIM + h * 64;
  for (int idx = t; idx < 1024; idx += 256) {
    const int p = idx >> 4, d4 = (idx & 15) * 4;
    const size_t r = rowbase + (size_t)p * DIM + d4;
    const ushort4 kk = *(const ushort4*)&kb[r];
    const ushort4 vx = *(const ushort4*)&vb[r];
    const unsigned short ka[4] = {kk.x, kk.y, kk.z, kk.w};
    const unsigned short va[4] = {vx.x, vx.y, vx.z, vx.w};
#pragma unroll
    for (int j = 0; j < 4; ++j) {
      const float z = b2f(ka[j]) * QK_SCALE;
      kps[p][d4 + j] = z > 0.f ? z + 1.f : __expf(z);   // elu(z)+1
      vv[p][d4 + j] = b2f(va[j]);
    }
  }
  __syncthreads();
  const int e4 = (t & 15) * 4, d4 = (t >> 4) * 4;
  float a[4][4] = {};
  for (int p = 0; p < 64; ++p) {
    const float4 kv = *(const float4*)&kps[p][d4];
    const float4 vx = *(const float4*)&vv[p][e4];
    const float kk[4] = {kv.x, kv.y, kv.z, kv.w};
    const float vb2[4] = {vx.x, vx.y, vx.z, vx.w};
#pragma unroll
    for (int i = 0; i < 4; ++i)
#pragma unroll
      for (int j = 0; j < 4; ++j) a[i][j] += kk[i] * vb2[j];
  }
  const size_t sb = (size_t)bid * 4096;
#pragma unroll
  for (int i = 0; i < 4; ++i) {
    float4 st; st.x = a[i][0]; st.y = a[i][1]; st.z = a[i][2]; st.w = a[i][3];
    *(float4*)&S[sb + (size_t)(d4 + i) * 64 + e4] = st;
  }
  if (t < 64) {
    float ssum = 0.f;
    for (int p = 0; p < 64; ++p) ssum += kps[p][t];
    ksum[(size_t)bid * 64 + t] = ssum;
  }
}

// In-place cumsum over buckets: 32*4096 chains of length 128 (stride 4096 floats)
__global__ void scan_S(float* __restrict__ S) {
  const int tid = blockIdx.x * 256 + threadIdx.x;
  const int bh = tid >> 12, de = tid & 4095;
  float* p = S + (size_t)bh * NBUCK * 4096 + de;
  float run = 0.f;
  for (int u = 0; u < NBUCK; ++u) { run += p[(size_t)u * 4096]; p[(size_t)u * 4096] = run; }
}

__global__ void scan_ksum(float* __restrict__ ks) {
  const int tid = blockIdx.x * 256 + threadIdx.x;
  if (tid >= 2048) return;
  const int bh = tid >> 6, d = tid & 63;
  float* p = ks + (size_t)bh * NBUCK * 64 + d;
  float run = 0.f;
  for (int u = 0; u < NBUCK; ++u) { run += p[u * 64]; p[u * 64] = run; }
}

// Per bucket u: attn = softmax(q*scale) @ (Ccum[u-1] / (kcum[u-1]+eps)); u=0 -> 0.
// Writes attn directly as bf16 hi/lo split in (b*SEQ+t, h*64+e) layout.
__global__ __launch_bounds__(256) void attn_out(
    const unsigned short* __restrict__ qb, const float* __restrict__ S,
    const float* __restrict__ ks,
    unsigned short* __restrict__ Ahi, unsigned short* __restrict__ Alo)
{
  const int bid = blockIdx.x;
  const int u = bid & 127, bh = bid >> 7;
  const int b = bh >> 4, h = bh & 15;
  const int t = threadIdx.x, l = t & 63, w = t >> 6;
  if (u == 0) {
    const size_t orow = (size_t)b * SEQ + (size_t)w * 16;
#pragma unroll
    for (int i = 0; i < 16; ++i) {
      Ahi[(orow + i) * DIM + h * 64 + l] = 0;
      Alo[(orow + i) * DIM + h * 64 + l] = 0;
    }
    return;
  }
  __shared__ float cc[64][64];
  __shared__ float qnT[64][68];
  __shared__ float recip[64];
  __shared__ float part[64][4];
  __shared__ float rowstat[64];
  const size_t sb = ((size_t)bh * NBUCK + (u - 1)) * 4096;
  for (int idx = t; idx < 4096; idx += 256) ((float*)cc)[idx] = S[sb + idx];
  if (t < 64) recip[t] = 1.f / (ks[((size_t)bh * NBUCK + (u - 1)) * 64 + t] + 1e-6f);
  const int p = t >> 2, c = t & 3;
  const size_t qrow = ((size_t)b * SEQ + (size_t)u * 64 + p) * DIM + h * 64 + c * 16;
  float qv[16];
#pragma unroll
  for (int ii = 0; ii < 4; ++ii) {
    const ushort4 qq = *(const ushort4*)&qb[qrow + ii * 4];
    qv[ii * 4 + 0] = b2f(qq.x) * QK_SCALE;
    qv[ii * 4 + 1] = b2f(qq.y) * QK_SCALE;
    qv[ii * 4 + 2] = b2f(qq.z) * QK_SCALE;
    qv[ii * 4 + 3] = b2f(qq.w) * QK_SCALE;
  }
  float mx = qv[0];
#pragma unroll
  for (int i = 1; i < 16; ++i) mx = fmaxf(mx, qv[i]);
  part[p][c] = mx;
  __syncthreads();
  if (c == 0) rowstat[p] = fmaxf(fmaxf(part[p][0], part[p][1]), fmaxf(part[p][2], part[p][3]));
  __syncthreads();
  const float rm = rowstat[p];
  float sum = 0.f;
#pragma unroll
  for (int i = 0; i < 16; ++i) { qv[i] = __expf(qv[i] - rm); sum += qv[i]; }
  part[p][c] = sum;
  __syncthreads();
  if (c == 0) rowstat[p] = part[p][0] + part[p][1] + part[p][2] + part[p][3];
  __syncthreads();
  const float inv = 1.f / rowstat[p];
#pragma unroll
  for (int i = 0; i < 16; ++i) qnT[c * 16 + i][p] = qv[i] * inv * recip[c * 16 + i];
  __syncthreads();
  // attn[p][e=l] = sum_d qn[p][d] * cc[d][e];  thread: e=l, rows w*16..w*16+15
  float acc[16] = {};
  for (int d = 0; d < 64; ++d) {
    const float cv = cc[d][l];
    const float4 q0 = *(const float4*)&qnT[d][w * 16 + 0];
    const float4 q1 = *(const float4*)&qnT[d][w * 16 + 4];
    const float4 q2 = *(const float4*)&qnT[d][w * 16 + 8];
    const float4 q3 = *(const float4*)&qnT[d][w * 16 + 12];
    acc[0]  += q0.x * cv; acc[1]  += q0.y * cv; acc[2]  += q0.z * cv; acc[3]  += q0.w * cv;
    acc[4]  += q1.x * cv; acc[5]  += q1.y * cv; acc[6]  += q1.z * cv; acc[7]  += q1.w * cv;
    acc[8]  += q2.x * cv; acc[9]  += q2.y * cv; acc[10] += q2.z * cv; acc[11] += q2.w * cv;
    acc[12] += q3.x * cv; acc[13] += q3.y * cv; acc[14] += q3.z * cv; acc[15] += q3.w * cv;
  }
  const size_t orow = (size_t)b * SEQ + (size_t)u * 64 + (size_t)w * 16;
#pragma unroll
  for (int i = 0; i < 16; ++i) {
    const float v2 = acc[i];
    const unsigned short hbits = f2b(v2);
    Ahi[(orow + i) * DIM + h * 64 + l] = hbits;
    Alo[(orow + i) * DIM + h * 64 + l] = f2b(v2 - b2f(hbits));
  }
}

extern "C" void kernel_launch(void* const* d_in, const int* in_sizes, int n_in,
                              void* d_out, int out_size, void* d_ws, size_t ws_size,
                              hipStream_t stream) {
  const float* x  = (const float*)d_in[0];
  const float* Wq = (const float*)d_in[1];
  const float* Wk = (const float*)d_in[2];
  const float* Wv = (const float*)d_in[3];
  const float* Wo = (const float*)d_in[4];
  const float* bo = (const float*)d_in[5];
  float* out = (float*)d_out;

  char* ws = (char*)d_ws;
  size_t off = 0;
  auto carve = [&](size_t bytes) -> void* {
    void* pp = ws + off;
    off += (bytes + 255) & ~(size_t)255;
    return pp;
  };
  // Region A: xhi+xlo (64 MiB), later overlaid by S (fp32, 64 MiB)
  unsigned short* xhi  = (unsigned short*)carve((size_t)MROWS * DIM * 2);
  unsigned short* xlo  = (unsigned short*)carve((size_t)MROWS * DIM * 2);
  float* S = (float*)xhi;                       // overlay (xhi/xlo dead after qkv gemm)
  // Weight splits: 16 MiB
  unsigned short* wchi = (unsigned short*)carve((size_t)3 * DIM * DIM * 2);
  unsigned short* wclo = (unsigned short*)carve((size_t)3 * DIM * DIM * 2);
  unsigned short* wohi = (unsigned short*)carve((size_t)DIM * DIM * 2);
  unsigned short* wolo = (unsigned short*)carve((size_t)DIM * DIM * 2);
  // q/k/v bf16: 96 MiB; kb/vb overlaid by ahi/alo after bucket_stats
  unsigned short* qb = (unsigned short*)carve((size_t)MROWS * DIM * 2);
  unsigned short* kb = (unsigned short*)carve((size_t)MROWS * DIM * 2);
  unsigned short* vb = (unsigned short*)carve((size_t)MROWS * DIM * 2);
  unsigned short* ahi = kb;                     // overlay
  unsigned short* alo = vb;                     // overlay
  float* ksum = (float*)carve((size_t)32 * NBUCK * 64 * 4);
  if (off > ws_size) {                          // diagnostic: encode ws_size in out[0]
    ws_sentinel<<<1, 1, 0, stream>>>(out, (float)ws_size);
    return;
  }

  split4<<<4096, 256, 0, stream>>>((const float4*)x, (ushort4*)xhi, (ushort4*)xlo, MROWS * DIM / 4);
  split4<<<1024, 256, 0, stream>>>((const float4*)Wq, (ushort4*)wchi, (ushort4*)wclo, DIM * DIM / 4);
  split4<<<1024, 256, 0, stream>>>((const float4*)Wk, (ushort4*)(wchi + DIM * DIM), (ushort4*)(wclo + DIM * DIM), DIM * DIM / 4);
  split4<<<1024, 256, 0, stream>>>((const float4*)Wv, (ushort4*)(wchi + 2 * DIM * DIM), (ushort4*)(wclo + 2 * DIM * DIM), DIM * DIM / 4);
  split4<<<1024, 256, 0, stream>>>((const float4*)Wo, (ushort4*)wohi, (ushort4*)wolo, DIM * DIM / 4);

  gemm3<1><<<dim3(QKVLD / 128, MROWS / 128), 256, 0, stream>>>(
      xhi, xlo, wchi, wclo, nullptr, qb, kb, vb, MROWS, QKVLD, DIM, 0, nullptr);
  bucket_stats<<<4096, 256, 0, stream>>>(kb, vb, S, ksum);
  scan_S<<<512, 256, 0, stream>>>(S);
  scan_ksum<<<8, 256, 0, stream>>>(ksum);
  attn_out<<<4096, 256, 0, stream>>>(qb, S, ksum, ahi, alo);
  gemm3<0><<<dim3(DIM / 128, MROWS / 128), 256, 0, stream>>>(
      ahi, alo, wohi, wolo, out, nullptr, nullptr, nullptr, MROWS, DIM, DIM, DIM, bo);
}

// Round 3
// 468.314 us; speedup vs baseline: 1.6054x; 1.6054x over previous
//
#include <hip/hip_runtime.h>

typedef short short8 __attribute__((ext_vector_type(8)));
typedef float floatx4 __attribute__((ext_vector_type(4)));

#define NBATCH 2
#define SEQ 8192
#define DIM 1024
#define QKVLD 3072
#define NBUCK 128
#define MROWS 16384
#define QK_SCALE 0.35355339059327379f

static __device__ __forceinline__ unsigned short f2b(float f) {
  unsigned int u = __float_as_uint(f);
  u = (u + 0x7fffu + ((u >> 16) & 1u)) >> 16;
  return (unsigned short)u;
}
static __device__ __forceinline__ float b2f(unsigned short h) {
  return __uint_as_float(((unsigned int)h) << 16);
}

__device__ __forceinline__ void gload_lds16(const void* g, void* l) {
  __builtin_amdgcn_global_load_lds(
      (const __attribute__((address_space(1))) unsigned int*)g,
      (__attribute__((address_space(3))) unsigned int*)l, 16, 0, 0);
}

__global__ void ws_sentinel(float* out, float v) { out[0] = v; }

// fp32 -> bf16 cast (x4 vectorized)
__global__ void cast4(const float4* __restrict__ src, ushort4* __restrict__ hi, int n4) {
  const int stride = gridDim.x * blockDim.x;
  for (int i = blockIdx.x * blockDim.x + threadIdx.x; i < n4; i += stride) {
    float4 v = src[i];
    ushort4 h;
    h.x = f2b(v.x); h.y = f2b(v.y); h.z = f2b(v.z); h.w = f2b(v.w);
    hi[i] = h;
  }
}

// fp32 -> bf16 hi + bf16 residual lo (weights only now)
__global__ void split4(const float4* __restrict__ src, ushort4* __restrict__ hi,
                       ushort4* __restrict__ lo, int n4) {
  const int stride = gridDim.x * blockDim.x;
  for (int i = blockIdx.x * blockDim.x + threadIdx.x; i < n4; i += stride) {
    float4 v = src[i];
    ushort4 h, l;
    h.x = f2b(v.x); l.x = f2b(v.x - b2f(h.x));
    h.y = f2b(v.y); l.y = f2b(v.y - b2f(h.y));
    h.z = f2b(v.z); l.z = f2b(v.z - b2f(h.z));
    h.w = f2b(v.w); l.w = f2b(v.w - b2f(h.w));
    hi[i] = h; lo[i] = l;
  }
}

// C[m][n] = sum_k A[m][k]*(Bhi[n][k]+Blo[n][k]) — fused 2-term split GEMM.
// 128x128 tile, BK=32, 4 waves (2x2 of 64x64), 16x16x32 bf16 MFMA.
// One barrier pair per K-step covers BOTH B-terms (A tile shared).
// EPI=0: fp32 C + bias (ldc=DIM).  EPI=1: bf16 store to {qb,kb,vb} by col/1024.
template <int EPI>
__global__ __launch_bounds__(256) void gemm2(
    const unsigned short* __restrict__ A,
    const unsigned short* __restrict__ Bhi, const unsigned short* __restrict__ Blo,
    float* __restrict__ C, unsigned short* __restrict__ qb,
    unsigned short* __restrict__ kb, unsigned short* __restrict__ vb,
    int K, const float* __restrict__ bias)
{
  __shared__ unsigned short As[128 * 32];
  __shared__ unsigned short Bh[128 * 32];
  __shared__ unsigned short Bl[128 * 32];
  const int t = threadIdx.x;
  const int l = t & 63, w = t >> 6;
  const int wr = w >> 1, wc = w & 1;
  const int m0 = blockIdx.y * 128, n0 = blockIdx.x * 128;
  const int lr = l & 15, lk = (l >> 4) * 8;
  floatx4 acc[4][4] = {};
  for (int ks = 0; ks < K; ks += 32) {
#pragma unroll
    for (int j = 0; j < 2; ++j) {
      const int u = j * 256 + t;
      const int row = u >> 2, qc = u & 3;
      gload_lds16(A   + (size_t)(m0 + row) * K + ks + qc * 8, &As[u * 8]);
      gload_lds16(Bhi + (size_t)(n0 + row) * K + ks + qc * 8, &Bh[u * 8]);
      gload_lds16(Blo + (size_t)(n0 + row) * K + ks + qc * 8, &Bl[u * 8]);
    }
    __syncthreads();
    short8 a[4], bh[4], bl[4];
#pragma unroll
    for (int mi = 0; mi < 4; ++mi)
      a[mi] = *(const short8*)&As[(wr * 64 + mi * 16 + lr) * 32 + lk];
#pragma unroll
    for (int ni = 0; ni < 4; ++ni) {
      bh[ni] = *(const short8*)&Bh[(wc * 64 + ni * 16 + lr) * 32 + lk];
      bl[ni] = *(const short8*)&Bl[(wc * 64 + ni * 16 + lr) * 32 + lk];
    }
#pragma unroll
    for (int mi = 0; mi < 4; ++mi)
#pragma unroll
      for (int ni = 0; ni < 4; ++ni)
        acc[mi][ni] = __builtin_amdgcn_mfma_f32_16x16x32_bf16(a[mi], bh[ni], acc[mi][ni], 0, 0, 0);
#pragma unroll
    for (int mi = 0; mi < 4; ++mi)
#pragma unroll
      for (int ni = 0; ni < 4; ++ni)
        acc[mi][ni] = __builtin_amdgcn_mfma_f32_16x16x32_bf16(a[mi], bl[ni], acc[mi][ni], 0, 0, 0);
    __syncthreads();
  }
#pragma unroll
  for (int mi = 0; mi < 4; ++mi)
#pragma unroll
    for (int ni = 0; ni < 4; ++ni)
#pragma unroll
      for (int i = 0; i < 4; ++i) {
        const int row = m0 + wr * 64 + mi * 16 + (l >> 4) * 4 + i;
        const int col = n0 + wc * 64 + ni * 16 + lr;
        float v = acc[mi][ni][i];
        if (EPI == 0) {
          if (bias) v += bias[col];
          C[(size_t)row * DIM + col] = v;
        } else {
          const int sel = col >> 10;
          unsigned short* dst = (sel == 0) ? qb : (sel == 1 ? kb : vb);
          dst[(size_t)row * DIM + (col & 1023)] = f2b(v);
        }
      }
}

// Per-bucket: S[d][e] = sum_p psi(k)[p][d] * v[p][e]; ksum[d] = sum_p psi(k)[p][d]
__global__ __launch_bounds__(256) void bucket_stats(
    const unsigned short* __restrict__ kb, const unsigned short* __restrict__ vb,
    float* __restrict__ S, float* __restrict__ ksum)
{
  const int bid = blockIdx.x;           // bh*128 + u
  const int u = bid & 127, bh = bid >> 7;
  const int b = bh >> 4, h = bh & 15;
  const int t = threadIdx.x;
  __shared__ float kps[64][64];
  __shared__ float vv[64][64];
  const size_t rowbase = ((size_t)b * SEQ + (size_t)u * 64) * DIM + h * 64;
  for (int idx = t; idx < 1024; idx += 256) {
    const int p = idx >> 4, d4 = (idx & 15) * 4;
    const size_t r = rowbase + (size_t)p * DIM + d4;
    const ushort4 kk = *(const ushort4*)&kb[r];
    const ushort4 vx = *(const ushort4*)&vb[r];
    const unsigned short ka[4] = {kk.x, kk.y, kk.z, kk.w};
    const unsigned short va[4] = {vx.x, vx.y, vx.z, vx.w};
#pragma unroll
    for (int j = 0; j < 4; ++j) {
      const float z = b2f(ka[j]) * QK_SCALE;
      kps[p][d4 + j] = z > 0.f ? z + 1.f : __expf(z);   // elu(z)+1
      vv[p][d4 + j] = b2f(va[j]);
    }
  }
  __syncthreads();
  const int e4 = (t & 15) * 4, d4 = (t >> 4) * 4;
  float a[4][4] = {};
  for (int p = 0; p < 64; ++p) {
    const float4 kv = *(const float4*)&kps[p][d4];
    const float4 vx = *(const float4*)&vv[p][e4];
    const float kk[4] = {kv.x, kv.y, kv.z, kv.w};
    const float vb2[4] = {vx.x, vx.y, vx.z, vx.w};
#pragma unroll
    for (int i = 0; i < 4; ++i)
#pragma unroll
      for (int j = 0; j < 4; ++j) a[i][j] += kk[i] * vb2[j];
  }
  const size_t sb = (size_t)bid * 4096;
#pragma unroll
  for (int i = 0; i < 4; ++i) {
    float4 st; st.x = a[i][0]; st.y = a[i][1]; st.z = a[i][2]; st.w = a[i][3];
    *(float4*)&S[sb + (size_t)(d4 + i) * 64 + e4] = st;
  }
  if (t < 64) {
    float ssum = 0.f;
    for (int p = 0; p < 64; ++p) ssum += kps[p][t];
    ksum[(size_t)bid * 64 + t] = ssum;
  }
}

// In-place cumsum over buckets: 32*4096 chains of length 128 (stride 4096 floats)
__global__ void scan_S(float* __restrict__ S) {
  const int tid = blockIdx.x * 256 + threadIdx.x;
  const int bh = tid >> 12, de = tid & 4095;
  float* p = S + (size_t)bh * NBUCK * 4096 + de;
  float run = 0.f;
  for (int u = 0; u < NBUCK; ++u) { run += p[(size_t)u * 4096]; p[(size_t)u * 4096] = run; }
}

__global__ void scan_ksum(float* __restrict__ ks) {
  const int tid = blockIdx.x * 256 + threadIdx.x;
  if (tid >= 2048) return;
  const int bh = tid >> 6, d = tid & 63;
  float* p = ks + (size_t)bh * NBUCK * 64 + d;
  float run = 0.f;
  for (int u = 0; u < NBUCK; ++u) { run += p[u * 64]; p[u * 64] = run; }
}

// Per bucket u: attn = softmax(q*scale) @ (Ccum[u-1] / (kcum[u-1]+eps)); u=0 -> 0.
// Writes attn as single bf16 plane (A-side residual dropped; B-side split covers Wo).
__global__ __launch_bounds__(256) void attn_out(
    const unsigned short* __restrict__ qb, const float* __restrict__ S,
    const float* __restrict__ ks, unsigned short* __restrict__ ab)
{
  const int bid = blockIdx.x;
  const int u = bid & 127, bh = bid >> 7;
  const int b = bh >> 4, h = bh & 15;
  const int t = threadIdx.x, l = t & 63, w = t >> 6;
  if (u == 0) {
    const size_t orow = (size_t)b * SEQ + (size_t)w * 16;
#pragma unroll
    for (int i = 0; i < 16; ++i) ab[(orow + i) * DIM + h * 64 + l] = 0;
    return;
  }
  __shared__ float cc[64][64];
  __shared__ float qnT[64][68];
  __shared__ float recip[64];
  __shared__ float part[64][4];
  __shared__ float rowstat[64];
  const size_t sb = ((size_t)bh * NBUCK + (u - 1)) * 4096;
  for (int idx = t; idx < 4096; idx += 256) ((float*)cc)[idx] = S[sb + idx];
  if (t < 64) recip[t] = 1.f / (ks[((size_t)bh * NBUCK + (u - 1)) * 64 + t] + 1e-6f);
  const int p = t >> 2, c = t & 3;
  const size_t qrow = ((size_t)b * SEQ + (size_t)u * 64 + p) * DIM + h * 64 + c * 16;
  float qv[16];
#pragma unroll
  for (int ii = 0; ii < 4; ++ii) {
    const ushort4 qq = *(const ushort4*)&qb[qrow + ii * 4];
    qv[ii * 4 + 0] = b2f(qq.x) * QK_SCALE;
    qv[ii * 4 + 1] = b2f(qq.y) * QK_SCALE;
    qv[ii * 4 + 2] = b2f(qq.z) * QK_SCALE;
    qv[ii * 4 + 3] = b2f(qq.w) * QK_SCALE;
  }
  float mx = qv[0];
#pragma unroll
  for (int i = 1; i < 16; ++i) mx = fmaxf(mx, qv[i]);
  part[p][c] = mx;
  __syncthreads();
  if (c == 0) rowstat[p] = fmaxf(fmaxf(part[p][0], part[p][1]), fmaxf(part[p][2], part[p][3]));
  __syncthreads();
  const float rm = rowstat[p];
  float sum = 0.f;
#pragma unroll
  for (int i = 0; i < 16; ++i) { qv[i] = __expf(qv[i] - rm); sum += qv[i]; }
  part[p][c] = sum;
  __syncthreads();
  if (c == 0) rowstat[p] = part[p][0] + part[p][1] + part[p][2] + part[p][3];
  __syncthreads();
  const float inv = 1.f / rowstat[p];
#pragma unroll
  for (int i = 0; i < 16; ++i) qnT[c * 16 + i][p] = qv[i] * inv * recip[c * 16 + i];
  __syncthreads();
  // attn[p][e=l] = sum_d qn[p][d] * cc[d][e];  thread: e=l, rows w*16..w*16+15
  float acc[16] = {};
  for (int d = 0; d < 64; ++d) {
    const float cv = cc[d][l];
    const float4 q0 = *(const float4*)&qnT[d][w * 16 + 0];
    const float4 q1 = *(const float4*)&qnT[d][w * 16 + 4];
    const float4 q2 = *(const float4*)&qnT[d][w * 16 + 8];
    const float4 q3 = *(const float4*)&qnT[d][w * 16 + 12];
    acc[0]  += q0.x * cv; acc[1]  += q0.y * cv; acc[2]  += q0.z * cv; acc[3]  += q0.w * cv;
    acc[4]  += q1.x * cv; acc[5]  += q1.y * cv; acc[6]  += q1.z * cv; acc[7]  += q1.w * cv;
    acc[8]  += q2.x * cv; acc[9]  += q2.y * cv; acc[10] += q2.z * cv; acc[11] += q2.w * cv;
    acc[12] += q3.x * cv; acc[13] += q3.y * cv; acc[14] += q3.z * cv; acc[15] += q3.w * cv;
  }
  const size_t orow = (size_t)b * SEQ + (size_t)u * 64 + (size_t)w * 16;
#pragma unroll
  for (int i = 0; i < 16; ++i) ab[(orow + i) * DIM + h * 64 + l] = f2b(acc[i]);
}

extern "C" void kernel_launch(void* const* d_in, const int* in_sizes, int n_in,
                              void* d_out, int out_size, void* d_ws, size_t ws_size,
                              hipStream_t stream) {
  const float* x  = (const float*)d_in[0];
  const float* Wq = (const float*)d_in[1];
  const float* Wk = (const float*)d_in[2];
  const float* Wv = (const float*)d_in[3];
  const float* Wo = (const float*)d_in[4];
  const float* bo = (const float*)d_in[5];
  float* out = (float*)d_out;

  char* ws = (char*)d_ws;
  size_t off = 0;
  auto carve = [&](size_t bytes) -> void* {
    void* pp = ws + off;
    off += (bytes + 255) & ~(size_t)255;
    return pp;
  };
  // Persistent through attn phase:
  unsigned short* qb = (unsigned short*)carve((size_t)MROWS * DIM * 2);   // 32 MiB
  unsigned short* kb = (unsigned short*)carve((size_t)MROWS * DIM * 2);   // 32 MiB (ab overlays)
  unsigned short* vb = (unsigned short*)carve((size_t)MROWS * DIM * 2);   // 32 MiB
  unsigned short* wohi = (unsigned short*)carve((size_t)DIM * DIM * 2);   // 2 MiB
  unsigned short* wolo = (unsigned short*)carve((size_t)DIM * DIM * 2);   // 2 MiB
  float* ksum = (float*)carve((size_t)32 * NBUCK * 64 * 4);               // 1 MiB
  // 64 MiB scratch region: phase1 = xb(32) + wchi(6) + wclo(6); phase2+ = S(64, overlay)
  char* scratch = (char*)carve((size_t)32 * NBUCK * 4096 * 4);            // 64 MiB
  unsigned short* xb   = (unsigned short*)scratch;
  unsigned short* wchi = (unsigned short*)(scratch + (size_t)MROWS * DIM * 2);
  unsigned short* wclo = (unsigned short*)(scratch + (size_t)MROWS * DIM * 2 + (size_t)3 * DIM * DIM * 2);
  float* S = (float*)scratch;
  unsigned short* ab = kb;  // overlay (kb dead after bucket_stats)
  if (off > ws_size) {      // diagnostic: encode ws_size in out[0]
    ws_sentinel<<<1, 1, 0, stream>>>(out, (float)ws_size);
    return;
  }

  cast4<<<4096, 256, 0, stream>>>((const float4*)x, (ushort4*)xb, MROWS * DIM / 4);
  split4<<<1024, 256, 0, stream>>>((const float4*)Wq, (ushort4*)wchi, (ushort4*)wclo, DIM * DIM / 4);
  split4<<<1024, 256, 0, stream>>>((const float4*)Wk, (ushort4*)(wchi + DIM * DIM), (ushort4*)(wclo + DIM * DIM), DIM * DIM / 4);
  split4<<<1024, 256, 0, stream>>>((const float4*)Wv, (ushort4*)(wchi + 2 * DIM * DIM), (ushort4*)(wclo + 2 * DIM * DIM), DIM * DIM / 4);
  split4<<<1024, 256, 0, stream>>>((const float4*)Wo, (ushort4*)wohi, (ushort4*)wolo, DIM * DIM / 4);

  gemm2<1><<<dim3(QKVLD / 128, MROWS / 128), 256, 0, stream>>>(
      xb, wchi, wclo, nullptr, qb, kb, vb, DIM, nullptr);
  bucket_stats<<<4096, 256, 0, stream>>>(kb, vb, S, ksum);
  scan_S<<<512, 256, 0, stream>>>(S);
  scan_ksum<<<8, 256, 0, stream>>>(ksum);
  attn_out<<<4096, 256, 0, stream>>>(qb, S, ksum, ab);
  gemm2<0><<<dim3(DIM / 128, MROWS / 128), 256, 0, stream>>>(
      ab, wohi, wolo, out, nullptr, nullptr, nullptr, DIM, bo);
}

// Round 4
// 359.365 us; speedup vs baseline: 2.0921x; 1.3032x over previous
//
#include <hip/hip_runtime.h>

typedef short short8 __attribute__((ext_vector_type(8)));
typedef float floatx4 __attribute__((ext_vector_type(4)));

#define NBATCH 2
#define SEQ 8192
#define DIM 1024
#define QKVLD 3072
#define NBUCK 128
#define MROWS 16384
#define QK_SCALE 0.35355339059327379f

static __device__ __forceinline__ unsigned short f2b(float f) {
  unsigned int u = __float_as_uint(f);
  u = (u + 0x7fffu + ((u >> 16) & 1u)) >> 16;
  return (unsigned short)u;
}
static __device__ __forceinline__ float b2f(unsigned short h) {
  return __uint_as_float(((unsigned int)h) << 16);
}

__device__ __forceinline__ void gload_lds16(const void* g, void* l) {
  __builtin_amdgcn_global_load_lds(
      (const __attribute__((address_space(1))) unsigned int*)g,
      (__attribute__((address_space(3))) unsigned int*)l, 16, 0, 0);
}

__global__ void ws_sentinel(float* out, float v) { out[0] = v; }

static __device__ __forceinline__ ushort4 cast_u4(float4 v) {
  ushort4 h; h.x = f2b(v.x); h.y = f2b(v.y); h.z = f2b(v.z); h.w = f2b(v.w); return h;
}

// Fused prep: x -> bf16 cast; Wq/Wk/Wv -> bf16 cast (concat); Wo -> hi/lo split.
__global__ __launch_bounds__(256) void prep(
    const float4* __restrict__ x, const float4* __restrict__ Wq,
    const float4* __restrict__ Wk, const float4* __restrict__ Wv,
    const float4* __restrict__ Wo,
    ushort4* __restrict__ xb, ushort4* __restrict__ wchi,
    ushort4* __restrict__ wohi, ushort4* __restrict__ wolo)
{
  const int bid = blockIdx.x, t = threadIdx.x;
  if (bid < 4096) {                      // x: 16M floats = 4.19M float4
    for (int i = bid * 256 + t; i < MROWS * DIM / 4; i += 4096 * 256)
      xb[i] = cast_u4(x[i]);
  } else {
    const int r = bid - 4096;            // 0..1023
    const int m = r >> 8;                // matrix id
    const int base = (r & 255) * 256 + t;
    const int n4 = DIM * DIM / 4;        // 262144
    if (m < 3) {
      const float4* src = (m == 0) ? Wq : (m == 1 ? Wk : Wv);
      ushort4* dst = wchi + (size_t)m * n4;
      for (int i = base; i < n4; i += 65536) dst[i] = cast_u4(src[i]);
    } else {
      for (int i = base; i < n4; i += 65536) {
        float4 v = Wo[i];
        ushort4 h, l;
        h.x = f2b(v.x); l.x = f2b(v.x - b2f(h.x));
        h.y = f2b(v.y); l.y = f2b(v.y - b2f(h.y));
        h.z = f2b(v.z); l.z = f2b(v.z - b2f(h.z));
        h.w = f2b(v.w); l.w = f2b(v.w - b2f(h.w));
        wohi[i] = h; wolo[i] = l;
      }
    }
  }
}

// qkv GEMM: C[m][n] = sum_k A[m][k]*B[n][k], single bf16 term.
// 128x128 tile, BK=32, 4 waves (2x2 of 64x64), 16x16x32 bf16 MFMA.
// Epilogue: bf16 store to {qb,kb,vb} selected by col/1024.
__global__ __launch_bounds__(256) void gemm_qkv(
    const unsigned short* __restrict__ A, const unsigned short* __restrict__ B,
    unsigned short* __restrict__ qb, unsigned short* __restrict__ kb,
    unsigned short* __restrict__ vb, int K)
{
  __shared__ unsigned short As[128 * 32];
  __shared__ unsigned short Bs[128 * 32];
  const int t = threadIdx.x;
  const int l = t & 63, w = t >> 6;
  const int wr = w >> 1, wc = w & 1;
  const int m0 = blockIdx.y * 128, n0 = blockIdx.x * 128;
  const int lr = l & 15, lk = (l >> 4) * 8;
  floatx4 acc[4][4] = {};
  for (int ks = 0; ks < K; ks += 32) {
#pragma unroll
    for (int j = 0; j < 2; ++j) {
      const int u = j * 256 + t;
      const int row = u >> 2, qc = u & 3;
      gload_lds16(A + (size_t)(m0 + row) * K + ks + qc * 8, &As[u * 8]);
      gload_lds16(B + (size_t)(n0 + row) * K + ks + qc * 8, &Bs[u * 8]);
    }
    __syncthreads();
    short8 a[4], b[4];
#pragma unroll
    for (int mi = 0; mi < 4; ++mi)
      a[mi] = *(const short8*)&As[(wr * 64 + mi * 16 + lr) * 32 + lk];
#pragma unroll
    for (int ni = 0; ni < 4; ++ni)
      b[ni] = *(const short8*)&Bs[(wc * 64 + ni * 16 + lr) * 32 + lk];
#pragma unroll
    for (int mi = 0; mi < 4; ++mi)
#pragma unroll
      for (int ni = 0; ni < 4; ++ni)
        acc[mi][ni] = __builtin_amdgcn_mfma_f32_16x16x32_bf16(a[mi], b[ni], acc[mi][ni], 0, 0, 0);
    __syncthreads();
  }
#pragma unroll
  for (int mi = 0; mi < 4; ++mi)
#pragma unroll
    for (int ni = 0; ni < 4; ++ni)
#pragma unroll
      for (int i = 0; i < 4; ++i) {
        const int row = m0 + wr * 64 + mi * 16 + (l >> 4) * 4 + i;
        const int col = n0 + wc * 64 + ni * 16 + lr;
        const int sel = col >> 10;
        unsigned short* dst = (sel == 0) ? qb : (sel == 1 ? kb : vb);
        dst[(size_t)row * DIM + (col & 1023)] = f2b(acc[mi][ni][i]);
      }
}

// Out GEMM: C[m][n] = sum_k A[m][k]*(Bhi[n][k]+Blo[n][k]) + bias[n], fp32 out.
__global__ __launch_bounds__(256) void gemm_out(
    const unsigned short* __restrict__ A,
    const unsigned short* __restrict__ Bhi, const unsigned short* __restrict__ Blo,
    float* __restrict__ C, int K, const float* __restrict__ bias)
{
  __shared__ unsigned short As[128 * 32];
  __shared__ unsigned short Bh[128 * 32];
  __shared__ unsigned short Bl[128 * 32];
  const int t = threadIdx.x;
  const int l = t & 63, w = t >> 6;
  const int wr = w >> 1, wc = w & 1;
  const int m0 = blockIdx.y * 128, n0 = blockIdx.x * 128;
  const int lr = l & 15, lk = (l >> 4) * 8;
  floatx4 acc[4][4] = {};
  for (int ks = 0; ks < K; ks += 32) {
#pragma unroll
    for (int j = 0; j < 2; ++j) {
      const int u = j * 256 + t;
      const int row = u >> 2, qc = u & 3;
      gload_lds16(A   + (size_t)(m0 + row) * K + ks + qc * 8, &As[u * 8]);
      gload_lds16(Bhi + (size_t)(n0 + row) * K + ks + qc * 8, &Bh[u * 8]);
      gload_lds16(Blo + (size_t)(n0 + row) * K + ks + qc * 8, &Bl[u * 8]);
    }
    __syncthreads();
    short8 a[4], bh[4], bl[4];
#pragma unroll
    for (int mi = 0; mi < 4; ++mi)
      a[mi] = *(const short8*)&As[(wr * 64 + mi * 16 + lr) * 32 + lk];
#pragma unroll
    for (int ni = 0; ni < 4; ++ni) {
      bh[ni] = *(const short8*)&Bh[(wc * 64 + ni * 16 + lr) * 32 + lk];
      bl[ni] = *(const short8*)&Bl[(wc * 64 + ni * 16 + lr) * 32 + lk];
    }
#pragma unroll
    for (int mi = 0; mi < 4; ++mi)
#pragma unroll
      for (int ni = 0; ni < 4; ++ni)
        acc[mi][ni] = __builtin_amdgcn_mfma_f32_16x16x32_bf16(a[mi], bh[ni], acc[mi][ni], 0, 0, 0);
#pragma unroll
    for (int mi = 0; mi < 4; ++mi)
#pragma unroll
      for (int ni = 0; ni < 4; ++ni)
        acc[mi][ni] = __builtin_amdgcn_mfma_f32_16x16x32_bf16(a[mi], bl[ni], acc[mi][ni], 0, 0, 0);
    __syncthreads();
  }
#pragma unroll
  for (int mi = 0; mi < 4; ++mi)
#pragma unroll
    for (int ni = 0; ni < 4; ++ni)
#pragma unroll
      for (int i = 0; i < 4; ++i) {
        const int row = m0 + wr * 64 + mi * 16 + (l >> 4) * 4 + i;
        const int col = n0 + wc * 64 + ni * 16 + lr;
        C[(size_t)row * DIM + col] = acc[mi][ni][i] + bias[col];
      }
}

// Per-bucket: S[d][e] = sum_p psi(k)[p][d] * v[p][e]; ksum[d] = sum_p psi(k)[p][d]
__global__ __launch_bounds__(256) void bucket_stats(
    const unsigned short* __restrict__ kb, const unsigned short* __restrict__ vb,
    float* __restrict__ S, float* __restrict__ ksum)
{
  const int bid = blockIdx.x;           // bh*128 + u
  const int u = bid & 127, bh = bid >> 7;
  const int b = bh >> 4, h = bh & 15;
  const int t = threadIdx.x;
  __shared__ float kps[64][64];
  __shared__ float vv[64][64];
  const size_t rowbase = ((size_t)b * SEQ + (size_t)u * 64) * DIM + h * 64;
  for (int idx = t; idx < 1024; idx += 256) {
    const int p = idx >> 4, d4 = (idx & 15) * 4;
    const size_t r = rowbase + (size_t)p * DIM + d4;
    const ushort4 kk = *(const ushort4*)&kb[r];
    const ushort4 vx = *(const ushort4*)&vb[r];
    const unsigned short ka[4] = {kk.x, kk.y, kk.z, kk.w};
    const unsigned short va[4] = {vx.x, vx.y, vx.z, vx.w};
#pragma unroll
    for (int j = 0; j < 4; ++j) {
      const float z = b2f(ka[j]) * QK_SCALE;
      kps[p][d4 + j] = z > 0.f ? z + 1.f : __expf(z);   // elu(z)+1
      vv[p][d4 + j] = b2f(va[j]);
    }
  }
  __syncthreads();
  const int e4 = (t & 15) * 4, d4 = (t >> 4) * 4;
  float a[4][4] = {};
  for (int p = 0; p < 64; ++p) {
    const float4 kv = *(const float4*)&kps[p][d4];
    const float4 vx = *(const float4*)&vv[p][e4];
    const float kk[4] = {kv.x, kv.y, kv.z, kv.w};
    const float vb2[4] = {vx.x, vx.y, vx.z, vx.w};
#pragma unroll
    for (int i = 0; i < 4; ++i)
#pragma unroll
      for (int j = 0; j < 4; ++j) a[i][j] += kk[i] * vb2[j];
  }
  const size_t sb = (size_t)bid * 4096;
#pragma unroll
  for (int i = 0; i < 4; ++i) {
    float4 st; st.x = a[i][0]; st.y = a[i][1]; st.z = a[i][2]; st.w = a[i][3];
    *(float4*)&S[sb + (size_t)(d4 + i) * 64 + e4] = st;
  }
  if (t < 64) {
    float ssum = 0.f;
    for (int p = 0; p < 64; ++p) ssum += kps[p][t];
    ksum[(size_t)bid * 64 + t] = ssum;
  }
}

// In-place cumsum over buckets: 32*4096 chains of length 128 (stride 4096 floats)
__global__ void scan_S(float* __restrict__ S) {
  const int tid = blockIdx.x * 256 + threadIdx.x;
  const int bh = tid >> 12, de = tid & 4095;
  float* p = S + (size_t)bh * NBUCK * 4096 + de;
  float run = 0.f;
  for (int u = 0; u < NBUCK; ++u) { run += p[(size_t)u * 4096]; p[(size_t)u * 4096] = run; }
}

__global__ void scan_ksum(float* __restrict__ ks) {
  const int tid = blockIdx.x * 256 + threadIdx.x;
  if (tid >= 2048) return;
  const int bh = tid >> 6, d = tid & 63;
  float* p = ks + (size_t)bh * NBUCK * 64 + d;
  float run = 0.f;
  for (int u = 0; u < NBUCK; ++u) { run += p[u * 64]; p[u * 64] = run; }
}

// Per bucket u: attn = softmax(q*scale) @ (Ccum[u-1] / (kcum[u-1]+eps)); u=0 -> 0.
__global__ __launch_bounds__(256) void attn_out(
    const unsigned short* __restrict__ qb, const float* __restrict__ S,
    const float* __restrict__ ks, unsigned short* __restrict__ ab)
{
  const int bid = blockIdx.x;
  const int u = bid & 127, bh = bid >> 7;
  const int b = bh >> 4, h = bh & 15;
  const int t = threadIdx.x, l = t & 63, w = t >> 6;
  if (u == 0) {
    const size_t orow = (size_t)b * SEQ + (size_t)w * 16;
#pragma unroll
    for (int i = 0; i < 16; ++i) ab[(orow + i) * DIM + h * 64 + l] = 0;
    return;
  }
  __shared__ float cc[64][64];
  __shared__ float qnT[64][68];
  __shared__ float recip[64];
  __shared__ float part[64][4];
  __shared__ float rowstat[64];
  const size_t sb = ((size_t)bh * NBUCK + (u - 1)) * 4096;
  for (int idx = t; idx < 4096; idx += 256) ((float*)cc)[idx] = S[sb + idx];
  if (t < 64) recip[t] = 1.f / (ks[((size_t)bh * NBUCK + (u - 1)) * 64 + t] + 1e-6f);
  const int p = t >> 2, c = t & 3;
  const size_t qrow = ((size_t)b * SEQ + (size_t)u * 64 + p) * DIM + h * 64 + c * 16;
  float qv[16];
#pragma unroll
  for (int ii = 0; ii < 4; ++ii) {
    const ushort4 qq = *(const ushort4*)&qb[qrow + ii * 4];
    qv[ii * 4 + 0] = b2f(qq.x) * QK_SCALE;
    qv[ii * 4 + 1] = b2f(qq.y) * QK_SCALE;
    qv[ii * 4 + 2] = b2f(qq.z) * QK_SCALE;
    qv[ii * 4 + 3] = b2f(qq.w) * QK_SCALE;
  }
  float mx = qv[0];
#pragma unroll
  for (int i = 1; i < 16; ++i) mx = fmaxf(mx, qv[i]);
  part[p][c] = mx;
  __syncthreads();
  if (c == 0) rowstat[p] = fmaxf(fmaxf(part[p][0], part[p][1]), fmaxf(part[p][2], part[p][3]));
  __syncthreads();
  const float rm = rowstat[p];
  float sum = 0.f;
#pragma unroll
  for (int i = 0; i < 16; ++i) { qv[i] = __expf(qv[i] - rm); sum += qv[i]; }
  part[p][c] = sum;
  __syncthreads();
  if (c == 0) rowstat[p] = part[p][0] + part[p][1] + part[p][2] + part[p][3];
  __syncthreads();
  const float inv = 1.f / rowstat[p];
#pragma unroll
  for (int i = 0; i < 16; ++i) qnT[c * 16 + i][p] = qv[i] * inv * recip[c * 16 + i];
  __syncthreads();
  float acc[16] = {};
  for (int d = 0; d < 64; ++d) {
    const float cv = cc[d][l];
    const float4 q0 = *(const float4*)&qnT[d][w * 16 + 0];
    const float4 q1 = *(const float4*)&qnT[d][w * 16 + 4];
    const float4 q2 = *(const float4*)&qnT[d][w * 16 + 8];
    const float4 q3 = *(const float4*)&qnT[d][w * 16 + 12];
    acc[0]  += q0.x * cv; acc[1]  += q0.y * cv; acc[2]  += q0.z * cv; acc[3]  += q0.w * cv;
    acc[4]  += q1.x * cv; acc[5]  += q1.y * cv; acc[6]  += q1.z * cv; acc[7]  += q1.w * cv;
    acc[8]  += q2.x * cv; acc[9]  += q2.y * cv; acc[10] += q2.z * cv; acc[11] += q2.w * cv;
    acc[12] += q3.x * cv; acc[13] += q3.y * cv; acc[14] += q3.z * cv; acc[15] += q3.w * cv;
  }
  const size_t orow = (size_t)b * SEQ + (size_t)u * 64 + (size_t)w * 16;
#pragma unroll
  for (int i = 0; i < 16; ++i) ab[(orow + i) * DIM + h * 64 + l] = f2b(acc[i]);
}

extern "C" void kernel_launch(void* const* d_in, const int* in_sizes, int n_in,
                              void* d_out, int out_size, void* d_ws, size_t ws_size,
                              hipStream_t stream) {
  const float* x  = (const float*)d_in[0];
  const float* Wq = (const float*)d_in[1];
  const float* Wk = (const float*)d_in[2];
  const float* Wv = (const float*)d_in[3];
  const float* Wo = (const float*)d_in[4];
  const float* bo = (const float*)d_in[5];
  float* out = (float*)d_out;

  char* ws = (char*)d_ws;
  size_t off = 0;
  auto carve = [&](size_t bytes) -> void* {
    void* pp = ws + off;
    off += (bytes + 255) & ~(size_t)255;
    return pp;
  };
  unsigned short* qb = (unsigned short*)carve((size_t)MROWS * DIM * 2);   // 32 MiB
  unsigned short* kb = (unsigned short*)carve((size_t)MROWS * DIM * 2);   // 32 MiB (ab overlays)
  unsigned short* vb = (unsigned short*)carve((size_t)MROWS * DIM * 2);   // 32 MiB
  unsigned short* wohi = (unsigned short*)carve((size_t)DIM * DIM * 2);   // 2 MiB
  unsigned short* wolo = (unsigned short*)carve((size_t)DIM * DIM * 2);   // 2 MiB
  float* ksum = (float*)carve((size_t)32 * NBUCK * 64 * 4);               // 1 MiB
  // 64 MiB scratch: phase1 = xb(32) + wchi(6); phase2+ = S(64, overlay)
  char* scratch = (char*)carve((size_t)32 * NBUCK * 4096 * 4);
  unsigned short* xb   = (unsigned short*)scratch;
  unsigned short* wchi = (unsigned short*)(scratch + (size_t)MROWS * DIM * 2);
  float* S = (float*)scratch;
  unsigned short* ab = kb;  // overlay (kb dead after bucket_stats)
  if (off > ws_size) {
    ws_sentinel<<<1, 1, 0, stream>>>(out, (float)ws_size);
    return;
  }

  prep<<<5120, 256, 0, stream>>>((const float4*)x, (const float4*)Wq, (const float4*)Wk,
                                 (const float4*)Wv, (const float4*)Wo,
                                 (ushort4*)xb, (ushort4*)wchi, (ushort4*)wohi, (ushort4*)wolo);
  gemm_qkv<<<dim3(QKVLD / 128, MROWS / 128), 256, 0, stream>>>(xb, wchi, qb, kb, vb, DIM);
  bucket_stats<<<4096, 256, 0, stream>>>(kb, vb, S, ksum);
  scan_S<<<512, 256, 0, stream>>>(S);
  scan_ksum<<<8, 256, 0, stream>>>(ksum);
  attn_out<<<4096, 256, 0, stream>>>(qb, S, ksum, ab);
  gemm_out<<<dim3(DIM / 128, MROWS / 128), 256, 0, stream>>>(ab, wohi, wolo, out, DIM, bo);
}

// Round 5
// 347.923 us; speedup vs baseline: 2.1609x; 1.0329x over previous
//
#include <hip/hip_runtime.h>

typedef short short8 __attribute__((ext_vector_type(8)));
typedef float floatx4 __attribute__((ext_vector_type(4)));

#define NBATCH 2
#define SEQ 8192
#define DIM 1024
#define QKVLD 3072
#define NBUCK 128
#define MROWS 16384
#define QK_SCALE 0.35355339059327379f

static __device__ __forceinline__ unsigned short f2b(float f) {
  unsigned int u = __float_as_uint(f);
  u = (u + 0x7fffu + ((u >> 16) & 1u)) >> 16;
  return (unsigned short)u;
}
static __device__ __forceinline__ float b2f(unsigned short h) {
  return __uint_as_float(((unsigned int)h) << 16);
}

__device__ __forceinline__ void gload_lds16(const void* g, void* l) {
  __builtin_amdgcn_global_load_lds(
      (const __attribute__((address_space(1))) unsigned int*)g,
      (__attribute__((address_space(3))) unsigned int*)l, 16, 0, 0);
}

__global__ void ws_sentinel(float* out, float v) { out[0] = v; }

static __device__ __forceinline__ ushort4 cast_u4(float4 v) {
  ushort4 h; h.x = f2b(v.x); h.y = f2b(v.y); h.z = f2b(v.z); h.w = f2b(v.w); return h;
}

// Fused prep: x -> bf16 cast; Wq/Wk/Wv -> bf16 cast (concat); Wo -> hi/lo split.
__global__ __launch_bounds__(256) void prep(
    const float4* __restrict__ x, const float4* __restrict__ Wq,
    const float4* __restrict__ Wk, const float4* __restrict__ Wv,
    const float4* __restrict__ Wo,
    ushort4* __restrict__ xb, ushort4* __restrict__ wchi,
    ushort4* __restrict__ wohi, ushort4* __restrict__ wolo)
{
  const int bid = blockIdx.x, t = threadIdx.x;
  if (bid < 4096) {
    for (int i = bid * 256 + t; i < MROWS * DIM / 4; i += 4096 * 256)
      xb[i] = cast_u4(x[i]);
  } else {
    const int r = bid - 4096;            // 0..1023
    const int m = r >> 8;                // matrix id
    const int base = (r & 255) * 256 + t;
    const int n4 = DIM * DIM / 4;        // 262144
    if (m < 3) {
      const float4* src = (m == 0) ? Wq : (m == 1 ? Wk : Wv);
      ushort4* dst = wchi + (size_t)m * n4;
      for (int i = base; i < n4; i += 65536) dst[i] = cast_u4(src[i]);
    } else {
      for (int i = base; i < n4; i += 65536) {
        float4 v = Wo[i];
        ushort4 h, l;
        h.x = f2b(v.x); l.x = f2b(v.x - b2f(h.x));
        h.y = f2b(v.y); l.y = f2b(v.y - b2f(h.y));
        h.z = f2b(v.z); l.z = f2b(v.z - b2f(h.z));
        h.w = f2b(v.w); l.w = f2b(v.w - b2f(h.w));
        wohi[i] = h; wolo[i] = l;
      }
    }
  }
}

// qkv GEMM: C[m][n] = sum_k A[m][k]*B[n][k], bf16 MFMA 16x16x32.
// 256x256 tile, BK=32, 8 waves (2Mx4N, each 128x64 out), double-buffered LDS,
// counted vmcnt(4) pipeline: next K-tile's global_load_lds stay in flight
// across the barrier while current tile's MFMAs run (T3/T4 mechanism).
// Epilogue: bf16 store to {qb,kb,vb} selected by col/1024.
__global__ __launch_bounds__(512) void gemm_qkv(
    const unsigned short* __restrict__ A, const unsigned short* __restrict__ B,
    unsigned short* __restrict__ qb, unsigned short* __restrict__ kb,
    unsigned short* __restrict__ vb, int K)
{
  __shared__ unsigned short As[2][256 * 32];   // 2 x 16 KiB
  __shared__ unsigned short Bs[2][256 * 32];   // 2 x 16 KiB  (total 64 KiB)
  const int t = threadIdx.x;
  const int l = t & 63, w = t >> 6;            // 8 waves
  const int wr = w >> 2, wc = w & 3;           // 2 x 4 wave grid
  // XCD-aware bijective swizzle: grid = 12 x 64 = 768 blocks, 768 % 8 == 0.
  const int bid0 = blockIdx.y * 12 + blockIdx.x;
  const int swz = (bid0 & 7) * 96 + (bid0 >> 3);
  const int m0 = (swz / 12) * 256, n0 = (swz % 12) * 256;
  const int lr = l & 15, lk = (l >> 4) * 8;
  const int kt = K >> 5;                       // 32 K-steps

  auto stage = [&](int buf, int ks) {
#pragma unroll
    for (int j = 0; j < 2; ++j) {
      const int idx = j * 512 + t;
      const int row = idx >> 2, qc = idx & 3;  // 256 rows x 4 chunks of 8 shorts
      gload_lds16(A + (size_t)(m0 + row) * K + ks + qc * 8, &As[buf][idx * 8]);
      gload_lds16(B + (size_t)(n0 + row) * K + ks + qc * 8, &Bs[buf][idx * 8]);
    }
  };

  floatx4 acc[8][4] = {};
  stage(0, 0);
  for (int s = 0; s < kt; ++s) {
    const int cur = s & 1;
    if (s + 1 < kt) {
      stage(cur ^ 1, (s + 1) << 5);
      asm volatile("s_waitcnt vmcnt(4)" ::: "memory");   // own tile-s loads done
    } else {
      asm volatile("s_waitcnt vmcnt(0)" ::: "memory");
    }
    __builtin_amdgcn_s_barrier();                        // all waves' tile-s parts in LDS
    __builtin_amdgcn_sched_barrier(0);
    short8 a[8], b[4];
#pragma unroll
    for (int mi = 0; mi < 8; ++mi)
      a[mi] = *(const short8*)&As[cur][(wr * 128 + mi * 16 + lr) * 32 + lk];
#pragma unroll
    for (int ni = 0; ni < 4; ++ni)
      b[ni] = *(const short8*)&Bs[cur][(wc * 64 + ni * 16 + lr) * 32 + lk];
    __builtin_amdgcn_s_setprio(1);
#pragma unroll
    for (int mi = 0; mi < 8; ++mi)
#pragma unroll
      for (int ni = 0; ni < 4; ++ni)
        acc[mi][ni] = __builtin_amdgcn_mfma_f32_16x16x32_bf16(a[mi], b[ni], acc[mi][ni], 0, 0, 0);
    __builtin_amdgcn_s_setprio(0);
    __builtin_amdgcn_sched_barrier(0);
    __builtin_amdgcn_s_barrier();                        // reads done before next overwrite
    __builtin_amdgcn_sched_barrier(0);
  }
#pragma unroll
  for (int mi = 0; mi < 8; ++mi)
#pragma unroll
    for (int ni = 0; ni < 4; ++ni)
#pragma unroll
      for (int i = 0; i < 4; ++i) {
        const int row = m0 + wr * 128 + mi * 16 + (l >> 4) * 4 + i;
        const int col = n0 + wc * 64 + ni * 16 + lr;
        const int sel = col >> 10;
        unsigned short* dst = (sel == 0) ? qb : (sel == 1 ? kb : vb);
        dst[(size_t)row * DIM + (col & 1023)] = f2b(acc[mi][ni][i]);
      }
}

// Out GEMM (unchanged this round): C = A*(Bhi+Blo)^T + bias, 128x128, fp32 out.
__global__ __launch_bounds__(256) void gemm_out(
    const unsigned short* __restrict__ A,
    const unsigned short* __restrict__ Bhi, const unsigned short* __restrict__ Blo,
    float* __restrict__ C, int K, const float* __restrict__ bias)
{
  __shared__ unsigned short As[128 * 32];
  __shared__ unsigned short Bh[128 * 32];
  __shared__ unsigned short Bl[128 * 32];
  const int t = threadIdx.x;
  const int l = t & 63, w = t >> 6;
  const int wr = w >> 1, wc = w & 1;
  const int m0 = blockIdx.y * 128, n0 = blockIdx.x * 128;
  const int lr = l & 15, lk = (l >> 4) * 8;
  floatx4 acc[4][4] = {};
  for (int ks = 0; ks < K; ks += 32) {
#pragma unroll
    for (int j = 0; j < 2; ++j) {
      const int u = j * 256 + t;
      const int row = u >> 2, qc = u & 3;
      gload_lds16(A   + (size_t)(m0 + row) * K + ks + qc * 8, &As[u * 8]);
      gload_lds16(Bhi + (size_t)(n0 + row) * K + ks + qc * 8, &Bh[u * 8]);
      gload_lds16(Blo + (size_t)(n0 + row) * K + ks + qc * 8, &Bl[u * 8]);
    }
    __syncthreads();
    short8 a[4], bh[4], bl[4];
#pragma unroll
    for (int mi = 0; mi < 4; ++mi)
      a[mi] = *(const short8*)&As[(wr * 64 + mi * 16 + lr) * 32 + lk];
#pragma unroll
    for (int ni = 0; ni < 4; ++ni) {
      bh[ni] = *(const short8*)&Bh[(wc * 64 + ni * 16 + lr) * 32 + lk];
      bl[ni] = *(const short8*)&Bl[(wc * 64 + ni * 16 + lr) * 32 + lk];
    }
#pragma unroll
    for (int mi = 0; mi < 4; ++mi)
#pragma unroll
      for (int ni = 0; ni < 4; ++ni)
        acc[mi][ni] = __builtin_amdgcn_mfma_f32_16x16x32_bf16(a[mi], bh[ni], acc[mi][ni], 0, 0, 0);
#pragma unroll
    for (int mi = 0; mi < 4; ++mi)
#pragma unroll
      for (int ni = 0; ni < 4; ++ni)
        acc[mi][ni] = __builtin_amdgcn_mfma_f32_16x16x32_bf16(a[mi], bl[ni], acc[mi][ni], 0, 0, 0);
    __syncthreads();
  }
#pragma unroll
  for (int mi = 0; mi < 4; ++mi)
#pragma unroll
    for (int ni = 0; ni < 4; ++ni)
#pragma unroll
      for (int i = 0; i < 4; ++i) {
        const int row = m0 + wr * 64 + mi * 16 + (l >> 4) * 4 + i;
        const int col = n0 + wc * 64 + ni * 16 + lr;
        C[(size_t)row * DIM + col] = acc[mi][ni][i] + bias[col];
      }
}

// Per-bucket: S[d][e] = sum_p psi(k)[p][d] * v[p][e]; ksum[d] = sum_p psi(k)[p][d]
__global__ __launch_bounds__(256) void bucket_stats(
    const unsigned short* __restrict__ kb, const unsigned short* __restrict__ vb,
    float* __restrict__ S, float* __restrict__ ksum)
{
  const int bid = blockIdx.x;           // bh*128 + u
  const int u = bid & 127, bh = bid >> 7;
  const int b = bh >> 4, h = bh & 15;
  const int t = threadIdx.x;
  __shared__ float kps[64][64];
  __shared__ float vv[64][64];
  const size_t rowbase = ((size_t)b * SEQ + (size_t)u * 64) * DIM + h * 64;
  for (int idx = t; idx < 1024; idx += 256) {
    const int p = idx >> 4, d4 = (idx & 15) * 4;
    const size_t r = rowbase + (size_t)p * DIM + d4;
    const ushort4 kk = *(const ushort4*)&kb[r];
    const ushort4 vx = *(const ushort4*)&vb[r];
    const unsigned short ka[4] = {kk.x, kk.y, kk.z, kk.w};
    const unsigned short va[4] = {vx.x, vx.y, vx.z, vx.w};
#pragma unroll
    for (int j = 0; j < 4; ++j) {
      const float z = b2f(ka[j]) * QK_SCALE;
      kps[p][d4 + j] = z > 0.f ? z + 1.f : __expf(z);   // elu(z)+1
      vv[p][d4 + j] = b2f(va[j]);
    }
  }
  __syncthreads();
  const int e4 = (t & 15) * 4, d4 = (t >> 4) * 4;
  float a[4][4] = {};
  for (int p = 0; p < 64; ++p) {
    const float4 kv = *(const float4*)&kps[p][d4];
    const float4 vx = *(const float4*)&vv[p][e4];
    const float kk[4] = {kv.x, kv.y, kv.z, kv.w};
    const float vb2[4] = {vx.x, vx.y, vx.z, vx.w};
#pragma unroll
    for (int i = 0; i < 4; ++i)
#pragma unroll
      for (int j = 0; j < 4; ++j) a[i][j] += kk[i] * vb2[j];
  }
  const size_t sb = (size_t)bid * 4096;
#pragma unroll
  for (int i = 0; i < 4; ++i) {
    float4 st; st.x = a[i][0]; st.y = a[i][1]; st.z = a[i][2]; st.w = a[i][3];
    *(float4*)&S[sb + (size_t)(d4 + i) * 64 + e4] = st;
  }
  if (t < 64) {
    float ssum = 0.f;
    for (int p = 0; p < 64; ++p) ssum += kps[p][t];
    ksum[(size_t)bid * 64 + t] = ssum;
  }
}

// Fused cumsum over buckets for S (blocks 0..511) and ksum (blocks 512..519).
__global__ void scan_all(float* __restrict__ S, float* __restrict__ ks) {
  const int bid = blockIdx.x;
  if (bid < 512) {
    const int tid = bid * 256 + threadIdx.x;
    const int bh = tid >> 12, de = tid & 4095;
    float* p = S + (size_t)bh * NBUCK * 4096 + de;
    float run = 0.f;
    for (int u = 0; u < NBUCK; ++u) { run += p[(size_t)u * 4096]; p[(size_t)u * 4096] = run; }
  } else {
    const int tid = (bid - 512) * 256 + threadIdx.x;
    if (tid >= 2048) return;
    const int bh = tid >> 6, d = tid & 63;
    float* p = ks + (size_t)bh * NBUCK * 64 + d;
    float run = 0.f;
    for (int u = 0; u < NBUCK; ++u) { run += p[u * 64]; p[u * 64] = run; }
  }
}

// Per bucket u: attn = softmax(q*scale) @ (Ccum[u-1] / (kcum[u-1]+eps)); u=0 -> 0.
__global__ __launch_bounds__(256) void attn_out(
    const unsigned short* __restrict__ qb, const float* __restrict__ S,
    const float* __restrict__ ks, unsigned short* __restrict__ ab)
{
  const int bid = blockIdx.x;
  const int u = bid & 127, bh = bid >> 7;
  const int b = bh >> 4, h = bh & 15;
  const int t = threadIdx.x, l = t & 63, w = t >> 6;
  if (u == 0) {
    const size_t orow = (size_t)b * SEQ + (size_t)w * 16;
#pragma unroll
    for (int i = 0; i < 16; ++i) ab[(orow + i) * DIM + h * 64 + l] = 0;
    return;
  }
  __shared__ float cc[64][64];
  __shared__ float qnT[64][68];
  __shared__ float recip[64];
  __shared__ float part[64][4];
  __shared__ float rowstat[64];
  const size_t sb = ((size_t)bh * NBUCK + (u - 1)) * 4096;
  for (int idx = t; idx < 4096; idx += 256) ((float*)cc)[idx] = S[sb + idx];
  if (t < 64) recip[t] = 1.f / (ks[((size_t)bh * NBUCK + (u - 1)) * 64 + t] + 1e-6f);
  const int p = t >> 2, c = t & 3;
  const size_t qrow = ((size_t)b * SEQ + (size_t)u * 64 + p) * DIM + h * 64 + c * 16;
  float qv[16];
#pragma unroll
  for (int ii = 0; ii < 4; ++ii) {
    const ushort4 qq = *(const ushort4*)&qb[qrow + ii * 4];
    qv[ii * 4 + 0] = b2f(qq.x) * QK_SCALE;
    qv[ii * 4 + 1] = b2f(qq.y) * QK_SCALE;
    qv[ii * 4 + 2] = b2f(qq.z) * QK_SCALE;
    qv[ii * 4 + 3] = b2f(qq.w) * QK_SCALE;
  }
  float mx = qv[0];
#pragma unroll
  for (int i = 1; i < 16; ++i) mx = fmaxf(mx, qv[i]);
  part[p][c] = mx;
  __syncthreads();
  if (c == 0) rowstat[p] = fmaxf(fmaxf(part[p][0], part[p][1]), fmaxf(part[p][2], part[p][3]));
  __syncthreads();
  const float rm = rowstat[p];
  float sum = 0.f;
#pragma unroll
  for (int i = 0; i < 16; ++i) { qv[i] = __expf(qv[i] - rm); sum += qv[i]; }
  part[p][c] = sum;
  __syncthreads();
  if (c == 0) rowstat[p] = part[p][0] + part[p][1] + part[p][2] + part[p][3];
  __syncthreads();
  const float inv = 1.f / rowstat[p];
#pragma unroll
  for (int i = 0; i < 16; ++i) qnT[c * 16 + i][p] = qv[i] * inv * recip[c * 16 + i];
  __syncthreads();
  float acc[16] = {};
  for (int d = 0; d < 64; ++d) {
    const float cv = cc[d][l];
    const float4 q0 = *(const float4*)&qnT[d][w * 16 + 0];
    const float4 q1 = *(const float4*)&qnT[d][w * 16 + 4];
    const float4 q2 = *(const float4*)&qnT[d][w * 16 + 8];
    const float4 q3 = *(const float4*)&qnT[d][w * 16 + 12];
    acc[0]  += q0.x * cv; acc[1]  += q0.y * cv; acc[2]  += q0.z * cv; acc[3]  += q0.w * cv;
    acc[4]  += q1.x * cv; acc[5]  += q1.y * cv; acc[6]  += q1.z * cv; acc[7]  += q1.w * cv;
    acc[8]  += q2.x * cv; acc[9]  += q2.y * cv; acc[10] += q2.z * cv; acc[11] += q2.w * cv;
    acc[12] += q3.x * cv; acc[13] += q3.y * cv; acc[14] += q3.z * cv; acc[15] += q3.w * cv;
  }
  const size_t orow = (size_t)b * SEQ + (size_t)u * 64 + (size_t)w * 16;
#pragma unroll
  for (int i = 0; i < 16; ++i) ab[(orow + i) * DIM + h * 64 + l] = f2b(acc[i]);
}

extern "C" void kernel_launch(void* const* d_in, const int* in_sizes, int n_in,
                              void* d_out, int out_size, void* d_ws, size_t ws_size,
                              hipStream_t stream) {
  const float* x  = (const float*)d_in[0];
  const float* Wq = (const float*)d_in[1];
  const float* Wk = (const float*)d_in[2];
  const float* Wv = (const float*)d_in[3];
  const float* Wo = (const float*)d_in[4];
  const float* bo = (const float*)d_in[5];
  float* out = (float*)d_out;

  char* ws = (char*)d_ws;
  size_t off = 0;
  auto carve = [&](size_t bytes) -> void* {
    void* pp = ws + off;
    off += (bytes + 255) & ~(size_t)255;
    return pp;
  };
  unsigned short* qb = (unsigned short*)carve((size_t)MROWS * DIM * 2);   // 32 MiB
  unsigned short* kb = (unsigned short*)carve((size_t)MROWS * DIM * 2);   // 32 MiB (ab overlays)
  unsigned short* vb = (unsigned short*)carve((size_t)MROWS * DIM * 2);   // 32 MiB
  unsigned short* wohi = (unsigned short*)carve((size_t)DIM * DIM * 2);   // 2 MiB
  unsigned short* wolo = (unsigned short*)carve((size_t)DIM * DIM * 2);   // 2 MiB
  float* ksum = (float*)carve((size_t)32 * NBUCK * 64 * 4);               // 1 MiB
  // 64 MiB scratch: phase1 = xb(32) + wchi(6); phase2+ = S(64, overlay)
  char* scratch = (char*)carve((size_t)32 * NBUCK * 4096 * 4);
  unsigned short* xb   = (unsigned short*)scratch;
  unsigned short* wchi = (unsigned short*)(scratch + (size_t)MROWS * DIM * 2);
  float* S = (float*)scratch;
  unsigned short* ab = kb;  // overlay (kb dead after bucket_stats)
  if (off > ws_size) {
    ws_sentinel<<<1, 1, 0, stream>>>(out, (float)ws_size);
    return;
  }

  prep<<<5120, 256, 0, stream>>>((const float4*)x, (const float4*)Wq, (const float4*)Wk,
                                 (const float4*)Wv, (const float4*)Wo,
                                 (ushort4*)xb, (ushort4*)wchi, (ushort4*)wohi, (ushort4*)wolo);
  gemm_qkv<<<dim3(QKVLD / 256, MROWS / 256), 512, 0, stream>>>(xb, wchi, qb, kb, vb, DIM);
  bucket_stats<<<4096, 256, 0, stream>>>(kb, vb, S, ksum);
  scan_all<<<520, 256, 0, stream>>>(S, ksum);
  attn_out<<<4096, 256, 0, stream>>>(qb, S, ksum, ab);
  gemm_out<<<dim3(DIM / 128, MROWS / 128), 256, 0, stream>>>(ab, wohi, wolo, out, DIM, bo);
}

// Round 6
// 338.671 us; speedup vs baseline: 2.2199x; 1.0273x over previous
//
#include <hip/hip_runtime.h>

typedef short short8 __attribute__((ext_vector_type(8)));
typedef float floatx4 __attribute__((ext_vector_type(4)));

#define NBATCH 2
#define SEQ 8192
#define DIM 1024
#define QKVLD 3072
#define NBUCK 128
#define MROWS 16384
#define QK_SCALE 0.35355339059327379f

static __device__ __forceinline__ unsigned short f2b(float f) {
  unsigned int u = __float_as_uint(f);
  u = (u + 0x7fffu + ((u >> 16) & 1u)) >> 16;
  return (unsigned short)u;
}
static __device__ __forceinline__ float b2f(unsigned short h) {
  return __uint_as_float(((unsigned int)h) << 16);
}

__device__ __forceinline__ void gload_lds16(const void* g, void* l) {
  __builtin_amdgcn_global_load_lds(
      (const __attribute__((address_space(1))) unsigned int*)g,
      (__attribute__((address_space(3))) unsigned int*)l, 16, 0, 0);
}

__global__ void ws_sentinel(float* out, float v) { out[0] = v; }

static __device__ __forceinline__ ushort4 cast_u4(float4 v) {
  ushort4 h; h.x = f2b(v.x); h.y = f2b(v.y); h.z = f2b(v.z); h.w = f2b(v.w); return h;
}

// Fused prep: x -> bf16 cast; Wq/Wk/Wv -> bf16 cast (concat); Wo -> hi/lo split.
__global__ __launch_bounds__(256) void prep(
    const float4* __restrict__ x, const float4* __restrict__ Wq,
    const float4* __restrict__ Wk, const float4* __restrict__ Wv,
    const float4* __restrict__ Wo,
    ushort4* __restrict__ xb, ushort4* __restrict__ wchi,
    ushort4* __restrict__ wohi, ushort4* __restrict__ wolo)
{
  const int bid = blockIdx.x, t = threadIdx.x;
  if (bid < 4096) {
    for (int i = bid * 256 + t; i < MROWS * DIM / 4; i += 4096 * 256)
      xb[i] = cast_u4(x[i]);
  } else {
    const int r = bid - 4096;            // 0..1023
    const int m = r >> 8;                // matrix id
    const int base = (r & 255) * 256 + t;
    const int n4 = DIM * DIM / 4;        // 262144
    if (m < 3) {
      const float4* src = (m == 0) ? Wq : (m == 1 ? Wk : Wv);
      ushort4* dst = wchi + (size_t)m * n4;
      for (int i = base; i < n4; i += 65536) dst[i] = cast_u4(src[i]);
    } else {
      for (int i = base; i < n4; i += 65536) {
        float4 v = Wo[i];
        ushort4 h, l;
        h.x = f2b(v.x); l.x = f2b(v.x - b2f(h.x));
        h.y = f2b(v.y); l.y = f2b(v.y - b2f(h.y));
        h.z = f2b(v.z); l.z = f2b(v.z - b2f(h.z));
        h.w = f2b(v.w); l.w = f2b(v.w - b2f(h.w));
        wohi[i] = h; wolo[i] = l;
      }
    }
  }
}

// LDS chunk-XOR swizzle (T2): slot (row, qc) holds global 16B-chunk qc ^ ((row>>1)&3).
// Write side: pre-swizzle the GLOBAL source (global_load_lds dest stays linear).
// Read side: chunk' = chunk ^ ((row>>1)&3); for all fragment rows, (row>>1)&3 ==
// ((lane&15)>>1)&3 (row-base terms are multiples of 4 rows), so it's one per-lane const.

// qkv GEMM: 256x256 tile, BK=32, 8 waves (2Mx4N), double-buffered LDS,
// counted vmcnt(4) pipeline + T2 swizzle. Epilogue: bf16 -> {qb,kb,vb}.
__global__ __launch_bounds__(512) void gemm_qkv(
    const unsigned short* __restrict__ A, const unsigned short* __restrict__ B,
    unsigned short* __restrict__ qb, unsigned short* __restrict__ kb,
    unsigned short* __restrict__ vb, int K)
{
  __shared__ unsigned short As[2][256 * 32];   // 2 x 16 KiB
  __shared__ unsigned short Bs[2][256 * 32];   // 2 x 16 KiB  (total 64 KiB)
  const int t = threadIdx.x;
  const int l = t & 63, w = t >> 6;            // 8 waves
  const int wr = w >> 2, wc = w & 3;           // 2 x 4 wave grid
  // XCD-aware bijective swizzle: grid = 12 x 64 = 768 blocks, 768 % 8 == 0.
  const int bid0 = blockIdx.y * 12 + blockIdx.x;
  const int swz = (bid0 & 7) * 96 + (bid0 >> 3);
  const int m0 = (swz / 12) * 256, n0 = (swz % 12) * 256;
  const int lr = l & 15;
  const int lkx = (((l >> 4) ^ ((l >> 1) & 3))) * 8;   // swizzled chunk, shorts
  const int kt = K >> 5;                       // 32 K-steps

  auto stage = [&](int buf, int ks) {
#pragma unroll
    for (int j = 0; j < 2; ++j) {
      const int idx = j * 512 + t;
      const int row = idx >> 2, qc = idx & 3;  // 256 rows x 4 chunks of 8 shorts
      const int qcx = qc ^ ((row >> 1) & 3);   // pre-swizzled global chunk
      gload_lds16(A + (size_t)(m0 + row) * K + ks + qcx * 8, &As[buf][idx * 8]);
      gload_lds16(B + (size_t)(n0 + row) * K + ks + qcx * 8, &Bs[buf][idx * 8]);
    }
  };

  floatx4 acc[8][4] = {};
  stage(0, 0);
  for (int s = 0; s < kt; ++s) {
    const int cur = s & 1;
    if (s + 1 < kt) {
      stage(cur ^ 1, (s + 1) << 5);
      asm volatile("s_waitcnt vmcnt(4)" ::: "memory");   // own tile-s loads done
    } else {
      asm volatile("s_waitcnt vmcnt(0)" ::: "memory");
    }
    __builtin_amdgcn_s_barrier();                        // all waves' tile-s parts in LDS
    __builtin_amdgcn_sched_barrier(0);
    short8 a[8], b[4];
#pragma unroll
    for (int mi = 0; mi < 8; ++mi)
      a[mi] = *(const short8*)&As[cur][(wr * 128 + mi * 16 + lr) * 32 + lkx];
#pragma unroll
    for (int ni = 0; ni < 4; ++ni)
      b[ni] = *(const short8*)&Bs[cur][(wc * 64 + ni * 16 + lr) * 32 + lkx];
    __builtin_amdgcn_s_setprio(1);
#pragma unroll
    for (int mi = 0; mi < 8; ++mi)
#pragma unroll
      for (int ni = 0; ni < 4; ++ni)
        acc[mi][ni] = __builtin_amdgcn_mfma_f32_16x16x32_bf16(a[mi], b[ni], acc[mi][ni], 0, 0, 0);
    __builtin_amdgcn_s_setprio(0);
    __builtin_amdgcn_sched_barrier(0);
    __builtin_amdgcn_s_barrier();                        // reads done before next overwrite
    __builtin_amdgcn_sched_barrier(0);
  }
#pragma unroll
  for (int mi = 0; mi < 8; ++mi)
#pragma unroll
    for (int ni = 0; ni < 4; ++ni)
#pragma unroll
      for (int i = 0; i < 4; ++i) {
        const int row = m0 + wr * 128 + mi * 16 + (l >> 4) * 4 + i;
        const int col = n0 + wc * 64 + ni * 16 + lr;
        const int sel = col >> 10;
        unsigned short* dst = (sel == 0) ? qb : (sel == 1 ? kb : vb);
        dst[(size_t)row * DIM + (col & 1023)] = f2b(acc[mi][ni][i]);
      }
}

// Out GEMM: C = A*(Bhi+Blo)^T + bias, 128x128, fp32 out, + T2 swizzle.
__global__ __launch_bounds__(256) void gemm_out(
    const unsigned short* __restrict__ A,
    const unsigned short* __restrict__ Bhi, const unsigned short* __restrict__ Blo,
    float* __restrict__ C, int K, const float* __restrict__ bias)
{
  __shared__ unsigned short As[128 * 32];
  __shared__ unsigned short Bh[128 * 32];
  __shared__ unsigned short Bl[128 * 32];
  const int t = threadIdx.x;
  const int l = t & 63, w = t >> 6;
  const int wr = w >> 1, wc = w & 1;
  const int m0 = blockIdx.y * 128, n0 = blockIdx.x * 128;
  const int lr = l & 15;
  const int lkx = (((l >> 4) ^ ((l >> 1) & 3))) * 8;
  floatx4 acc[4][4] = {};
  for (int ks = 0; ks < K; ks += 32) {
#pragma unroll
    for (int j = 0; j < 2; ++j) {
      const int u = j * 256 + t;
      const int row = u >> 2, qc = u & 3;
      const int qcx = qc ^ ((row >> 1) & 3);
      gload_lds16(A   + (size_t)(m0 + row) * K + ks + qcx * 8, &As[u * 8]);
      gload_lds16(Bhi + (size_t)(n0 + row) * K + ks + qcx * 8, &Bh[u * 8]);
      gload_lds16(Blo + (size_t)(n0 + row) * K + ks + qcx * 8, &Bl[u * 8]);
    }
    __syncthreads();
    short8 a[4], bh[4], bl[4];
#pragma unroll
    for (int mi = 0; mi < 4; ++mi)
      a[mi] = *(const short8*)&As[(wr * 64 + mi * 16 + lr) * 32 + lkx];
#pragma unroll
    for (int ni = 0; ni < 4; ++ni) {
      bh[ni] = *(const short8*)&Bh[(wc * 64 + ni * 16 + lr) * 32 + lkx];
      bl[ni] = *(const short8*)&Bl[(wc * 64 + ni * 16 + lr) * 32 + lkx];
    }
#pragma unroll
    for (int mi = 0; mi < 4; ++mi)
#pragma unroll
      for (int ni = 0; ni < 4; ++ni)
        acc[mi][ni] = __builtin_amdgcn_mfma_f32_16x16x32_bf16(a[mi], bh[ni], acc[mi][ni], 0, 0, 0);
#pragma unroll
    for (int mi = 0; mi < 4; ++mi)
#pragma unroll
      for (int ni = 0; ni < 4; ++ni)
        acc[mi][ni] = __builtin_amdgcn_mfma_f32_16x16x32_bf16(a[mi], bl[ni], acc[mi][ni], 0, 0, 0);
    __syncthreads();
  }
#pragma unroll
  for (int mi = 0; mi < 4; ++mi)
#pragma unroll
    for (int ni = 0; ni < 4; ++ni)
#pragma unroll
      for (int i = 0; i < 4; ++i) {
        const int row = m0 + wr * 64 + mi * 16 + (l >> 4) * 4 + i;
        const int col = n0 + wc * 64 + ni * 16 + lr;
        C[(size_t)row * DIM + col] = acc[mi][ni][i] + bias[col];
      }
}

// Per-bucket: S[d][e] = sum_p psi(k)[p][d] * v[p][e]; ksum[d] = sum_p psi(k)[p][d]
__global__ __launch_bounds__(256) void bucket_stats(
    const unsigned short* __restrict__ kb, const unsigned short* __restrict__ vb,
    float* __restrict__ S, float* __restrict__ ksum)
{
  const int bid = blockIdx.x;           // bh*128 + u
  const int u = bid & 127, bh = bid >> 7;
  const int b = bh >> 4, h = bh & 15;
  const int t = threadIdx.x;
  __shared__ float kps[64][64];
  __shared__ float vv[64][64];
  const size_t rowbase = ((size_t)b * SEQ + (size_t)u * 64) * DIM + h * 64;
  for (int idx = t; idx < 1024; idx += 256) {
    const int p = idx >> 4, d4 = (idx & 15) * 4;
    const size_t r = rowbase + (size_t)p * DIM + d4;
    const ushort4 kk = *(const ushort4*)&kb[r];
    const ushort4 vx = *(const ushort4*)&vb[r];
    const unsigned short ka[4] = {kk.x, kk.y, kk.z, kk.w};
    const unsigned short va[4] = {vx.x, vx.y, vx.z, vx.w};
#pragma unroll
    for (int j = 0; j < 4; ++j) {
      const float z = b2f(ka[j]) * QK_SCALE;
      kps[p][d4 + j] = z > 0.f ? z + 1.f : __expf(z);   // elu(z)+1
      vv[p][d4 + j] = b2f(va[j]);
    }
  }
  __syncthreads();
  const int e4 = (t & 15) * 4, d4 = (t >> 4) * 4;
  float a[4][4] = {};
  for (int p = 0; p < 64; ++p) {
    const float4 kv = *(const float4*)&kps[p][d4];
    const float4 vx = *(const float4*)&vv[p][e4];
    const float kk[4] = {kv.x, kv.y, kv.z, kv.w};
    const float vb2[4] = {vx.x, vx.y, vx.z, vx.w};
#pragma unroll
    for (int i = 0; i < 4; ++i)
#pragma unroll
      for (int j = 0; j < 4; ++j) a[i][j] += kk[i] * vb2[j];
  }
  const size_t sb = (size_t)bid * 4096;
#pragma unroll
  for (int i = 0; i < 4; ++i) {
    float4 st; st.x = a[i][0]; st.y = a[i][1]; st.z = a[i][2]; st.w = a[i][3];
    *(float4*)&S[sb + (size_t)(d4 + i) * 64 + e4] = st;
  }
  if (t < 64) {
    float ssum = 0.f;
    for (int p = 0; p < 64; ++p) ssum += kps[p][t];
    ksum[(size_t)bid * 64 + t] = ssum;
  }
}

// Fused cumsum over buckets for S (blocks 0..511) and ksum (blocks 512..519).
__global__ void scan_all(float* __restrict__ S, float* __restrict__ ks) {
  const int bid = blockIdx.x;
  if (bid < 512) {
    const int tid = bid * 256 + threadIdx.x;
    const int bh = tid >> 12, de = tid & 4095;
    float* p = S + (size_t)bh * NBUCK * 4096 + de;
    float run = 0.f;
    for (int u = 0; u < NBUCK; ++u) { run += p[(size_t)u * 4096]; p[(size_t)u * 4096] = run; }
  } else {
    const int tid = (bid - 512) * 256 + threadIdx.x;
    if (tid >= 2048) return;
    const int bh = tid >> 6, d = tid & 63;
    float* p = ks + (size_t)bh * NBUCK * 64 + d;
    float run = 0.f;
    for (int u = 0; u < NBUCK; ++u) { run += p[u * 64]; p[u * 64] = run; }
  }
}

// Per bucket u: attn = softmax(q*scale) @ (Ccum[u-1] / (kcum[u-1]+eps)); u=0 -> 0.
__global__ __launch_bounds__(256) void attn_out(
    const unsigned short* __restrict__ qb, const float* __restrict__ S,
    const float* __restrict__ ks, unsigned short* __restrict__ ab)
{
  const int bid = blockIdx.x;
  const int u = bid & 127, bh = bid >> 7;
  const int b = bh >> 4, h = bh & 15;
  const int t = threadIdx.x, l = t & 63, w = t >> 6;
  if (u == 0) {
    const size_t orow = (size_t)b * SEQ + (size_t)w * 16;
#pragma unroll
    for (int i = 0; i < 16; ++i) ab[(orow + i) * DIM + h * 64 + l] = 0;
    return;
  }
  __shared__ float cc[64][64];
  __shared__ float qnT[64][68];
  __shared__ float recip[64];
  __shared__ float part[64][4];
  __shared__ float rowstat[64];
  const size_t sb = ((size_t)bh * NBUCK + (u - 1)) * 4096;
  for (int idx = t; idx < 4096; idx += 256) ((float*)cc)[idx] = S[sb + idx];
  if (t < 64) recip[t] = 1.f / (ks[((size_t)bh * NBUCK + (u - 1)) * 64 + t] + 1e-6f);
  const int p = t >> 2, c = t & 3;
  const size_t qrow = ((size_t)b * SEQ + (size_t)u * 64 + p) * DIM + h * 64 + c * 16;
  float qv[16];
#pragma unroll
  for (int ii = 0; ii < 4; ++ii) {
    const ushort4 qq = *(const ushort4*)&qb[qrow + ii * 4];
    qv[ii * 4 + 0] = b2f(qq.x) * QK_SCALE;
    qv[ii * 4 + 1] = b2f(qq.y) * QK_SCALE;
    qv[ii * 4 + 2] = b2f(qq.z) * QK_SCALE;
    qv[ii * 4 + 3] = b2f(qq.w) * QK_SCALE;
  }
  float mx = qv[0];
#pragma unroll
  for (int i = 1; i < 16; ++i) mx = fmaxf(mx, qv[i]);
  part[p][c] = mx;
  __syncthreads();
  if (c == 0) rowstat[p] = fmaxf(fmaxf(part[p][0], part[p][1]), fmaxf(part[p][2], part[p][3]));
  __syncthreads();
  const float rm = rowstat[p];
  float sum = 0.f;
#pragma unroll
  for (int i = 0; i < 16; ++i) { qv[i] = __expf(qv[i] - rm); sum += qv[i]; }
  part[p][c] = sum;
  __syncthreads();
  if (c == 0) rowstat[p] = part[p][0] + part[p][1] + part[p][2] + part[p][3];
  __syncthreads();
  const float inv = 1.f / rowstat[p];
#pragma unroll
  for (int i = 0; i < 16; ++i) qnT[c * 16 + i][p] = qv[i] * inv * recip[c * 16 + i];
  __syncthreads();
  float acc[16] = {};
  for (int d = 0; d < 64; ++d) {
    const float cv = cc[d][l];
    const float4 q0 = *(const float4*)&qnT[d][w * 16 + 0];
    const float4 q1 = *(const float4*)&qnT[d][w * 16 + 4];
    const float4 q2 = *(const float4*)&qnT[d][w * 16 + 8];
    const float4 q3 = *(const float4*)&qnT[d][w * 16 + 12];
    acc[0]  += q0.x * cv; acc[1]  += q0.y * cv; acc[2]  += q0.z * cv; acc[3]  += q0.w * cv;
    acc[4]  += q1.x * cv; acc[5]  += q1.y * cv; acc[6]  += q1.z * cv; acc[7]  += q1.w * cv;
    acc[8]  += q2.x * cv; acc[9]  += q2.y * cv; acc[10] += q2.z * cv; acc[11] += q2.w * cv;
    acc[12] += q3.x * cv; acc[13] += q3.y * cv; acc[14] += q3.z * cv; acc[15] += q3.w * cv;
  }
  const size_t orow = (size_t)b * SEQ + (size_t)u * 64 + (size_t)w * 16;
#pragma unroll
  for (int i = 0; i < 16; ++i) ab[(orow + i) * DIM + h * 64 + l] = f2b(acc[i]);
}

extern "C" void kernel_launch(void* const* d_in, const int* in_sizes, int n_in,
                              void* d_out, int out_size, void* d_ws, size_t ws_size,
                              hipStream_t stream) {
  const float* x  = (const float*)d_in[0];
  const float* Wq = (const float*)d_in[1];
  const float* Wk = (const float*)d_in[2];
  const float* Wv = (const float*)d_in[3];
  const float* Wo = (const float*)d_in[4];
  const float* bo = (const float*)d_in[5];
  float* out = (float*)d_out;

  char* ws = (char*)d_ws;
  size_t off = 0;
  auto carve = [&](size_t bytes) -> void* {
    void* pp = ws + off;
    off += (bytes + 255) & ~(size_t)255;
    return pp;
  };
  unsigned short* qb = (unsigned short*)carve((size_t)MROWS * DIM * 2);   // 32 MiB
  unsigned short* kb = (unsigned short*)carve((size_t)MROWS * DIM * 2);   // 32 MiB (ab overlays)
  unsigned short* vb = (unsigned short*)carve((size_t)MROWS * DIM * 2);   // 32 MiB
  unsigned short* wohi = (unsigned short*)carve((size_t)DIM * DIM * 2);   // 2 MiB
  unsigned short* wolo = (unsigned short*)carve((size_t)DIM * DIM * 2);   // 2 MiB
  float* ksum = (float*)carve((size_t)32 * NBUCK * 64 * 4);               // 1 MiB
  // 64 MiB scratch: phase1 = xb(32) + wchi(6); phase2+ = S(64, overlay)
  char* scratch = (char*)carve((size_t)32 * NBUCK * 4096 * 4);
  unsigned short* xb   = (unsigned short*)scratch;
  unsigned short* wchi = (unsigned short*)(scratch + (size_t)MROWS * DIM * 2);
  float* S = (float*)scratch;
  unsigned short* ab = kb;  // overlay (kb dead after bucket_stats)
  if (off > ws_size) {
    ws_sentinel<<<1, 1, 0, stream>>>(out, (float)ws_size);
    return;
  }

  prep<<<5120, 256, 0, stream>>>((const float4*)x, (const float4*)Wq, (const float4*)Wk,
                                 (const float4*)Wv, (const float4*)Wo,
                                 (ushort4*)xb, (ushort4*)wchi, (ushort4*)wohi, (ushort4*)wolo);
  gemm_qkv<<<dim3(QKVLD / 256, MROWS / 256), 512, 0, stream>>>(xb, wchi, qb, kb, vb, DIM);
  bucket_stats<<<4096, 256, 0, stream>>>(kb, vb, S, ksum);
  scan_all<<<520, 256, 0, stream>>>(S, ksum);
  attn_out<<<4096, 256, 0, stream>>>(qb, S, ksum, ab);
  gemm_out<<<dim3(DIM / 128, MROWS / 128), 256, 0, stream>>>(ab, wohi, wolo, out, DIM, bo);
}

// Round 7
// 310.703 us; speedup vs baseline: 2.4197x; 1.0900x over previous
//
#include <hip/hip_runtime.h>

typedef short short8 __attribute__((ext_vector_type(8)));
typedef float floatx4 __attribute__((ext_vector_type(4)));

#define NBATCH 2
#define SEQ 8192
#define DIM 1024
#define QKVLD 3072
#define NBUCK 128
#define MROWS 16384
#define QK_SCALE 0.35355339059327379f

static __device__ __forceinline__ unsigned short f2b(float f) {
  unsigned int u = __float_as_uint(f);
  u = (u + 0x7fffu + ((u >> 16) & 1u)) >> 16;
  return (unsigned short)u;
}
static __device__ __forceinline__ float b2f(unsigned short h) {
  return __uint_as_float(((unsigned int)h) << 16);
}

__device__ __forceinline__ void gload_lds16(const void* g, void* l) {
  __builtin_amdgcn_global_load_lds(
      (const __attribute__((address_space(1))) unsigned int*)g,
      (__attribute__((address_space(3))) unsigned int*)l, 16, 0, 0);
}

__global__ void ws_sentinel(float* out, float v) { out[0] = v; }

static __device__ __forceinline__ ushort4 cast_u4(float4 v) {
  ushort4 h; h.x = f2b(v.x); h.y = f2b(v.y); h.z = f2b(v.z); h.w = f2b(v.w); return h;
}

// Fused prep: x, Wq/Wk/Wv (concat), Wo -> bf16 cast.
__global__ __launch_bounds__(256) void prep(
    const float4* __restrict__ x, const float4* __restrict__ Wq,
    const float4* __restrict__ Wk, const float4* __restrict__ Wv,
    const float4* __restrict__ Wo,
    ushort4* __restrict__ xb, ushort4* __restrict__ wchi, ushort4* __restrict__ wob)
{
  const int bid = blockIdx.x, t = threadIdx.x;
  if (bid < 4096) {
    for (int i = bid * 256 + t; i < MROWS * DIM / 4; i += 4096 * 256)
      xb[i] = cast_u4(x[i]);
  } else {
    const int r = bid - 4096;            // 0..1023
    const int m = r >> 8;                // matrix id
    const int base = (r & 255) * 256 + t;
    const int n4 = DIM * DIM / 4;        // 262144
    const float4* src = (m == 0) ? Wq : (m == 1 ? Wk : (m == 2 ? Wv : Wo));
    ushort4* dst = (m < 3) ? (wchi + (size_t)m * n4) : wob;
    for (int i = base; i < n4; i += 65536) dst[i] = cast_u4(src[i]);
  }
}

// Unified 256x256 GEMM: C[m][n] = sum_k A[m][k]*B[n][k], bf16 MFMA 16x16x32.
// BK=32, 8 waves (2Mx4N, each 128x64 out), double-buffered LDS, counted
// vmcnt(4) pipeline (T3/T4), chunk-XOR LDS swizzle (T2, both sides),
// bijective XCD swizzle (T1), setprio around MFMA (T5), B-first/A-pipelined
// inner loop so MFMA(0,*) depends on 5 reads not 12.
// EPI=1: bf16 epilogue -> {qb,kb,vb} by col/1024.  EPI=0: fp32 + bias -> C.
// NCB = N-tile count (grid.x); grid = dim3(NCB, M/256), nwg % 8 == 0.
template <int EPI, int NCB>
__global__ __launch_bounds__(512) void gemm256(
    const unsigned short* __restrict__ A, const unsigned short* __restrict__ B,
    unsigned short* __restrict__ qb, unsigned short* __restrict__ kb,
    unsigned short* __restrict__ vb,
    float* __restrict__ C, const float* __restrict__ bias, int K)
{
  __shared__ unsigned short As[2][256 * 32];   // 2 x 16 KiB
  __shared__ unsigned short Bs[2][256 * 32];   // 2 x 16 KiB  (total 64 KiB)
  const int t = threadIdx.x;
  const int l = t & 63, w = t >> 6;            // 8 waves
  const int wr = w >> 2, wc = w & 3;           // 2 x 4 wave grid
  const int bid0 = blockIdx.y * NCB + blockIdx.x;
  const int swz = (bid0 & 7) * (NCB * 8) + (bid0 >> 3);   // bijective, nwg%8==0
  const int m0 = (swz / NCB) * 256, n0 = (swz % NCB) * 256;
  const int lr = l & 15;
  const int lkx = (((l >> 4) ^ ((l >> 1) & 3))) * 8;   // swizzled chunk (shorts)
  const int kt = K >> 5;

  auto stage = [&](int buf, int ks) {
#pragma unroll
    for (int j = 0; j < 2; ++j) {
      const int idx = j * 512 + t;
      const int row = idx >> 2, qc = idx & 3;  // 256 rows x 4 chunks of 8 shorts
      const int qcx = qc ^ ((row >> 1) & 3);   // pre-swizzled global chunk
      gload_lds16(A + (size_t)(m0 + row) * K + ks + qcx * 8, &As[buf][idx * 8]);
      gload_lds16(B + (size_t)(n0 + row) * K + ks + qcx * 8, &Bs[buf][idx * 8]);
    }
  };

  floatx4 acc[8][4] = {};
  stage(0, 0);
  for (int s = 0; s < kt; ++s) {
    const int cur = s & 1;
    if (s + 1 < kt) {
      stage(cur ^ 1, (s + 1) << 5);
      asm volatile("s_waitcnt vmcnt(4)" ::: "memory");   // own tile-s loads landed
    } else {
      asm volatile("s_waitcnt vmcnt(0)" ::: "memory");
    }
    __builtin_amdgcn_s_barrier();                        // tile s fully in LDS
    __builtin_amdgcn_sched_barrier(0);
    short8 bfr[4];
#pragma unroll
    for (int ni = 0; ni < 4; ++ni)
      bfr[ni] = *(const short8*)&Bs[cur][(wc * 64 + ni * 16 + lr) * 32 + lkx];
    short8 acur = *(const short8*)&As[cur][(wr * 128 + lr) * 32 + lkx];
    __builtin_amdgcn_s_setprio(1);
#pragma unroll
    for (int mi = 0; mi < 8; ++mi) {
      short8 anx;
      if (mi < 7) anx = *(const short8*)&As[cur][(wr * 128 + (mi + 1) * 16 + lr) * 32 + lkx];
      acc[mi][0] = __builtin_amdgcn_mfma_f32_16x16x32_bf16(acur, bfr[0], acc[mi][0], 0, 0, 0);
      acc[mi][1] = __builtin_amdgcn_mfma_f32_16x16x32_bf16(acur, bfr[1], acc[mi][1], 0, 0, 0);
      acc[mi][2] = __builtin_amdgcn_mfma_f32_16x16x32_bf16(acur, bfr[2], acc[mi][2], 0, 0, 0);
      acc[mi][3] = __builtin_amdgcn_mfma_f32_16x16x32_bf16(acur, bfr[3], acc[mi][3], 0, 0, 0);
      if (mi < 7) acur = anx;
    }
    __builtin_amdgcn_s_setprio(0);
    __builtin_amdgcn_sched_barrier(0);
    __builtin_amdgcn_s_barrier();                        // reads done before overwrite
    __builtin_amdgcn_sched_barrier(0);
  }
#pragma unroll
  for (int mi = 0; mi < 8; ++mi)
#pragma unroll
    for (int ni = 0; ni < 4; ++ni)
#pragma unroll
      for (int i = 0; i < 4; ++i) {
        const int row = m0 + wr * 128 + mi * 16 + (l >> 4) * 4 + i;
        const int col = n0 + wc * 64 + ni * 16 + lr;
        if (EPI == 0) {
          C[(size_t)row * DIM + col] = acc[mi][ni][i] + bias[col];
        } else {
          const int sel = col >> 10;
          unsigned short* dst = (sel == 0) ? qb : (sel == 1 ? kb : vb);
          dst[(size_t)row * DIM + (col & 1023)] = f2b(acc[mi][ni][i]);
        }
      }
}

// Per-bucket: S[d][e] = sum_p psi(k)[p][d] * v[p][e]; ksum[d] = sum_p psi(k)[p][d]
__global__ __launch_bounds__(256) void bucket_stats(
    const unsigned short* __restrict__ kb, const unsigned short* __restrict__ vb,
    float* __restrict__ S, float* __restrict__ ksum)
{
  const int bid = blockIdx.x;           // bh*128 + u
  const int u = bid & 127, bh = bid >> 7;
  const int b = bh >> 4, h = bh & 15;
  const int t = threadIdx.x;
  __shared__ float kps[64][64];
  __shared__ float vv[64][64];
  const size_t rowbase = ((size_t)b * SEQ + (size_t)u * 64) * DIM + h * 64;
  for (int idx = t; idx < 1024; idx += 256) {
    const int p = idx >> 4, d4 = (idx & 15) * 4;
    const size_t r = rowbase + (size_t)p * DIM + d4;
    const ushort4 kk = *(const ushort4*)&kb[r];
    const ushort4 vx = *(const ushort4*)&vb[r];
    const unsigned short ka[4] = {kk.x, kk.y, kk.z, kk.w};
    const unsigned short va[4] = {vx.x, vx.y, vx.z, vx.w};
#pragma unroll
    for (int j = 0; j < 4; ++j) {
      const float z = b2f(ka[j]) * QK_SCALE;
      kps[p][d4 + j] = z > 0.f ? z + 1.f : __expf(z);   // elu(z)+1
      vv[p][d4 + j] = b2f(va[j]);
    }
  }
  __syncthreads();
  const int e4 = (t & 15) * 4, d4 = (t >> 4) * 4;
  float a[4][4] = {};
  for (int p = 0; p < 64; ++p) {
    const float4 kv = *(const float4*)&kps[p][d4];
    const float4 vx = *(const float4*)&vv[p][e4];
    const float kk[4] = {kv.x, kv.y, kv.z, kv.w};
    const float vb2[4] = {vx.x, vx.y, vx.z, vx.w};
#pragma unroll
    for (int i = 0; i < 4; ++i)
#pragma unroll
      for (int j = 0; j < 4; ++j) a[i][j] += kk[i] * vb2[j];
  }
  const size_t sb = (size_t)bid * 4096;
#pragma unroll
  for (int i = 0; i < 4; ++i) {
    float4 st; st.x = a[i][0]; st.y = a[i][1]; st.z = a[i][2]; st.w = a[i][3];
    *(float4*)&S[sb + (size_t)(d4 + i) * 64 + e4] = st;
  }
  if (t < 64) {
    float ssum = 0.f;
    for (int p = 0; p < 64; ++p) ssum += kps[p][t];
    ksum[(size_t)bid * 64 + t] = ssum;
  }
}

// Fused cumsum over buckets for S (blocks 0..511) and ksum (blocks 512..519).
__global__ void scan_all(float* __restrict__ S, float* __restrict__ ks) {
  const int bid = blockIdx.x;
  if (bid < 512) {
    const int tid = bid * 256 + threadIdx.x;
    const int bh = tid >> 12, de = tid & 4095;
    float* p = S + (size_t)bh * NBUCK * 4096 + de;
    float run = 0.f;
    for (int u = 0; u < NBUCK; ++u) { run += p[(size_t)u * 4096]; p[(size_t)u * 4096] = run; }
  } else {
    const int tid = (bid - 512) * 256 + threadIdx.x;
    if (tid >= 2048) return;
    const int bh = tid >> 6, d = tid & 63;
    float* p = ks + (size_t)bh * NBUCK * 64 + d;
    float run = 0.f;
    for (int u = 0; u < NBUCK; ++u) { run += p[u * 64]; p[u * 64] = run; }
  }
}

// Per bucket u: attn = softmax(q*scale) @ (Ccum[u-1] / (kcum[u-1]+eps)); u=0 -> 0.
__global__ __launch_bounds__(256) void attn_out(
    const unsigned short* __restrict__ qb, const float* __restrict__ S,
    const float* __restrict__ ks, unsigned short* __restrict__ ab)
{
  const int bid = blockIdx.x;
  const int u = bid & 127, bh = bid >> 7;
  const int b = bh >> 4, h = bh & 15;
  const int t = threadIdx.x, l = t & 63, w = t >> 6;
  if (u == 0) {
    const size_t orow = (size_t)b * SEQ + (size_t)w * 16;
#pragma unroll
    for (int i = 0; i < 16; ++i) ab[(orow + i) * DIM + h * 64 + l] = 0;
    return;
  }
  __shared__ float cc[64][64];
  __shared__ float qnT[64][68];
  __shared__ float recip[64];
  __shared__ float part[64][4];
  __shared__ float rowstat[64];
  const size_t sb = ((size_t)bh * NBUCK + (u - 1)) * 4096;
  for (int idx = t; idx < 4096; idx += 256) ((float*)cc)[idx] = S[sb + idx];
  if (t < 64) recip[t] = 1.f / (ks[((size_t)bh * NBUCK + (u - 1)) * 64 + t] + 1e-6f);
  const int p = t >> 2, c = t & 3;
  const size_t qrow = ((size_t)b * SEQ + (size_t)u * 64 + p) * DIM + h * 64 + c * 16;
  float qv[16];
#pragma unroll
  for (int ii = 0; ii < 4; ++ii) {
    const ushort4 qq = *(const ushort4*)&qb[qrow + ii * 4];
    qv[ii * 4 + 0] = b2f(qq.x) * QK_SCALE;
    qv[ii * 4 + 1] = b2f(qq.y) * QK_SCALE;
    qv[ii * 4 + 2] = b2f(qq.z) * QK_SCALE;
    qv[ii * 4 + 3] = b2f(qq.w) * QK_SCALE;
  }
  float mx = qv[0];
#pragma unroll
  for (int i = 1; i < 16; ++i) mx = fmaxf(mx, qv[i]);
  part[p][c] = mx;
  __syncthreads();
  if (c == 0) rowstat[p] = fmaxf(fmaxf(part[p][0], part[p][1]), fmaxf(part[p][2], part[p][3]));
  __syncthreads();
  const float rm = rowstat[p];
  float sum = 0.f;
#pragma unroll
  for (int i = 0; i < 16; ++i) { qv[i] = __expf(qv[i] - rm); sum += qv[i]; }
  part[p][c] = sum;
  __syncthreads();
  if (c == 0) rowstat[p] = part[p][0] + part[p][1] + part[p][2] + part[p][3];
  __syncthreads();
  const float inv = 1.f / rowstat[p];
#pragma unroll
  for (int i = 0; i < 16; ++i) qnT[c * 16 + i][p] = qv[i] * inv * recip[c * 16 + i];
  __syncthreads();
  float acc[16] = {};
  for (int d = 0; d < 64; ++d) {
    const float cv = cc[d][l];
    const float4 q0 = *(const float4*)&qnT[d][w * 16 + 0];
    const float4 q1 = *(const float4*)&qnT[d][w * 16 + 4];
    const float4 q2 = *(const float4*)&qnT[d][w * 16 + 8];
    const float4 q3 = *(const float4*)&qnT[d][w * 16 + 12];
    acc[0]  += q0.x * cv; acc[1]  += q0.y * cv; acc[2]  += q0.z * cv; acc[3]  += q0.w * cv;
    acc[4]  += q1.x * cv; acc[5]  += q1.y * cv; acc[6]  += q1.z * cv; acc[7]  += q1.w * cv;
    acc[8]  += q2.x * cv; acc[9]  += q2.y * cv; acc[10] += q2.z * cv; acc[11] += q2.w * cv;
    acc[12] += q3.x * cv; acc[13] += q3.y * cv; acc[14] += q3.z * cv; acc[15] += q3.w * cv;
  }
  const size_t orow = (size_t)b * SEQ + (size_t)u * 64 + (size_t)w * 16;
#pragma unroll
  for (int i = 0; i < 16; ++i) ab[(orow + i) * DIM + h * 64 + l] = f2b(acc[i]);
}

extern "C" void kernel_launch(void* const* d_in, const int* in_sizes, int n_in,
                              void* d_out, int out_size, void* d_ws, size_t ws_size,
                              hipStream_t stream) {
  const float* x  = (const float*)d_in[0];
  const float* Wq = (const float*)d_in[1];
  const float* Wk = (const float*)d_in[2];
  const float* Wv = (const float*)d_in[3];
  const float* Wo = (const float*)d_in[4];
  const float* bo = (const float*)d_in[5];
  float* out = (float*)d_out;

  char* ws = (char*)d_ws;
  size_t off = 0;
  auto carve = [&](size_t bytes) -> void* {
    void* pp = ws + off;
    off += (bytes + 255) & ~(size_t)255;
    return pp;
  };
  unsigned short* qb = (unsigned short*)carve((size_t)MROWS * DIM * 2);   // 32 MiB
  unsigned short* kb = (unsigned short*)carve((size_t)MROWS * DIM * 2);   // 32 MiB (ab overlays)
  unsigned short* vb = (unsigned short*)carve((size_t)MROWS * DIM * 2);   // 32 MiB
  unsigned short* wob = (unsigned short*)carve((size_t)DIM * DIM * 2);    // 2 MiB
  float* ksum = (float*)carve((size_t)32 * NBUCK * 64 * 4);               // 1 MiB
  // 64 MiB scratch: phase1 = xb(32) + wchi(6); phase2+ = S(64, overlay)
  char* scratch = (char*)carve((size_t)32 * NBUCK * 4096 * 4);
  unsigned short* xb   = (unsigned short*)scratch;
  unsigned short* wchi = (unsigned short*)(scratch + (size_t)MROWS * DIM * 2);
  float* S = (float*)scratch;
  unsigned short* ab = kb;  // overlay (kb dead after bucket_stats)
  if (off > ws_size) {
    ws_sentinel<<<1, 1, 0, stream>>>(out, (float)ws_size);
    return;
  }

  prep<<<5120, 256, 0, stream>>>((const float4*)x, (const float4*)Wq, (const float4*)Wk,
                                 (const float4*)Wv, (const float4*)Wo,
                                 (ushort4*)xb, (ushort4*)wchi, (ushort4*)wob);
  gemm256<1, 12><<<dim3(12, 64), 512, 0, stream>>>(
      xb, wchi, qb, kb, vb, nullptr, nullptr, DIM);
  bucket_stats<<<4096, 256, 0, stream>>>(kb, vb, S, ksum);
  scan_all<<<520, 256, 0, stream>>>(S, ksum);
  attn_out<<<4096, 256, 0, stream>>>(qb, S, ksum, ab);
  gemm256<0, 4><<<dim3(4, 64), 512, 0, stream>>>(
      ab, wob, nullptr, nullptr, nullptr, out, bo, DIM);
}